// Round 13
// baseline (1732.032 us; speedup 1.0000x reference)
//
#include <hip/hip_runtime.h>
#include <hip/hip_bf16.h>
#include <cstddef>

#define T_ 64
#define N_ 1024
#define L_ 16
#define H_ 256
#define STATE_ 290
#define EKSTR 296   // enc hbf row stride (ushorts): 592B = 37*16, b128-aligned

typedef short s16x8 __attribute__((ext_vector_type(8)));
typedef float f32x4 __attribute__((ext_vector_type(4)));
typedef ushort us4 __attribute__((ext_vector_type(4)));
typedef ushort us8 __attribute__((ext_vector_type(8)));
#define MFMA16 __builtin_amdgcn_mfma_f32_16x16x32_bf16

// raw barrier: wait LDS ops only, do NOT drain global stores.
#define BAR() asm volatile("s_waitcnt lgkmcnt(0)\n\ts_barrier" ::: "memory")

__device__ __forceinline__ float b2f(ushort u){ return __uint_as_float(((unsigned)u) << 16); }
__device__ __forceinline__ ushort f2b(float f){
  unsigned x = __float_as_uint(f);
  return (ushort)((x + 0x7FFFu + ((x >> 16) & 1u)) >> 16);
}
__device__ __forceinline__ float gruh(float gir,float giz,float gig,
                                      float ghr,float ghz,float ghg,float hp){
  float r = 1.f/(1.f + __expf(-(gir + ghr)));
  float z = 1.f/(1.f + __expf(-(giz + ghz)));
  float g = tanhf(gig + r*ghg);
  return (1.f - z)*g + z*hp;
}

// ---------- fused weight prep: all permutes/converts in ONE launch ----------
__global__ void prep_all(
    const float* __restrict__ wih_e, const float* __restrict__ whh_e,
    ushort* __restrict__ wihe_p, ushort* __restrict__ whhe_p,
    const float* __restrict__ wih_c, const float* __restrict__ whh_c,
    ushort* __restrict__ wihc_p, ushort* __restrict__ whhc_p,
    const float* __restrict__ bih_c, const float* __restrict__ bhh_c, float* __restrict__ cb,
    const float* __restrict__ W1, ushort* __restrict__ W1b,
    const float* __restrict__ W2, ushort* __restrict__ W2b,
    const float* __restrict__ Wa, ushort* __restrict__ WaTb){
  int b = blockIdx.x, t = threadIdx.x;
  if (b < 832) {                       // perm wih_e [771,256] -> [832,256]
    int idx = b*256 + t;
    int d = idx >> 8, c = idx & 255;
    int tile = d >> 4, uu = d & 15;
    int k = tile/3, p = tile - 3*k;
    int hc = k*16 + uu;
    bool ok = (tile < 51) && (hc < 257);
    wihe_p[idx] = ok ? f2b(wih_e[(size_t)(p*257 + hc)*256 + c]) : (ushort)0;
  } else if (b < 1768) {               // perm whh_e [771,257] -> [832,288]
    int idx = (b-832)*256 + t;
    int d = idx / 288, c = idx - d*288;
    int tile = d >> 4, uu = d & 15;
    int k = tile/3, p = tile - 3*k;
    int hc = k*16 + uu;
    bool ok = (tile < 51) && (hc < 257) && (c < 257);
    whhe_p[idx] = ok ? f2b(whh_e[(size_t)(p*257 + hc)*257 + c]) : (ushort)0;
  } else if (b < 2536) {               // perm wih_c [768,256]
    int idx = (b-1768)*256 + t;
    int d = idx >> 8, c = idx & 255;
    int tile = d >> 4, uu = d & 15;
    int k = tile/3, p = tile - 3*k;
    wihc_p[idx] = f2b(wih_c[(size_t)(p*256 + k*16 + uu)*256 + c]);
  } else if (b < 3304) {               // perm whh_c [768,256]
    int idx = (b-2536)*256 + t;
    int d = idx >> 8, c = idx & 255;
    int tile = d >> 4, uu = d & 15;
    int k = tile/3, p = tile - 3*k;
    whhc_p[idx] = f2b(whh_c[(size_t)(p*256 + k*16 + uu)*256 + c]);
  } else if (b < 3307) {               // cbias (r,z: bih+bhh; g: bih)
    int d = (b-3304)*256 + t;
    if (d < 768) {
      int tile = d >> 4, uu = d & 15;
      int k = tile/3, p = tile - 3*k;
      int src = p*256 + k*16 + uu;
      cb[d] = bih_c[src] + (p < 2 ? bhh_c[src] : 0.f);
    }
  } else if (b < 3627) {               // W1 convert [256,320]
    int idx = (b-3307)*256 + t;
    W1b[idx] = f2b(W1[idx]);
  } else if (b < 3883) {               // W2 convert [256,256]
    int idx = (b-3627)*256 + t;
    W2b[idx] = f2b(W2[idx]);
  } else {                             // Wa transpose -> bf16
    int m = b - 3883;
    WaTb[(size_t)t*256 + m] = f2b(Wa[(size_t)m*256 + t]);
  }
}

// ---------- fused embed + init_state + r0 ----------
__global__ void emb_init_r0(
    const int* __restrict__ lines, const float* __restrict__ emb, const float* __restrict__ hxs,
    ushort* __restrict__ Mbf, float* __restrict__ hbuf, float* __restrict__ p0,
    float* __restrict__ r0v){
  __shared__ ushort Ms[16][256];
  __shared__ float p0s[16];
  __shared__ int ls[16];
  __shared__ int nz;
  int n = blockIdx.x, t = threadIdx.x;
  if (t == 0) nz = 0;
  if (t < 16) ls[t] = lines[n*16 + t];
  __syncthreads();
  #pragma unroll
  for (int l = 0; l < 16; ++l) {
    ushort v = f2b(emb[(size_t)ls[l]*256 + t]);
    Ms[l][t] = v;
    Mbf[((size_t)n*16 + l)*256 + t] = v;
  }
  for (int c = t; c < STATE_; c += 256)
    if (hxs[(size_t)n*STATE_ + c] != 0.f) atomicOr(&nz, 1);
  __syncthreads();
  bool new_ep = (nz == 0);
  hbuf[(size_t)n*256 + t] = hxs[(size_t)n*STATE_ + 2 + t];
  if (t < 16) {
    float pv = hxs[(size_t)n*STATE_ + 2 + 256 + 16 + t];
    if (t == 0 && new_ep) pv = 1.f;
    p0[n*16 + t] = pv;
    p0s[t] = pv;
  }
  __syncthreads();
  float s = 0.f;
  #pragma unroll
  for (int l = 0; l < 16; ++l) s += p0s[l]*b2f(Ms[l][t]);
  r0v[(size_t)n*256 + t] = s;
}

__global__ void build_xcat8(const float* __restrict__ cond, const int* __restrict__ act,
                            const float* __restrict__ r0v, const ushort* __restrict__ Mbf,
                            ushort* __restrict__ xcat){
  int idx = blockIdx.x*256 + threadIdx.x;
  if (idx >= T_*N_*40) return;
  int kc = idx % 40;
  int row = idx / 40;
  int n = row & 1023, t = row >> 10;
  us8 v;
  if (kc < 8) {
    const float* cp = cond + (size_t)row*64 + kc*8;
    #pragma unroll
    for (int i = 0; i < 8; ++i) v[i] = f2b(cp[i]);
  } else if (t == 0) {
    const float* rp = r0v + (size_t)n*256 + (kc-8)*8;
    #pragma unroll
    for (int i = 0; i < 8; ++i) v[i] = f2b(rp[i]);
  } else {
    int a = act[(size_t)(t-1)*1024 + n];
    v = *(const us8*)(Mbf + ((size_t)n*16 + a)*256 + (kc-8)*8);
  }
  *(us8*)(xcat + (size_t)idx*8) = v;
}

// ---------- MFMA GEMM: out[r,col] = act(sum_k A[r,k]*W[col,k] + bias[col]), bf16 out ----------
template<int RELU>
__global__ __launch_bounds__(256) void gemm_mfma(
    const ushort* __restrict__ A, const ushort* __restrict__ W,
    const float* __restrict__ bias, ushort* __restrict__ out,
    int Kd, int ldo){
  int lane = threadIdx.x & 63, wv = threadIdx.x >> 6;
  int u = lane & 15, g4 = lane >> 4;
  int br = blockIdx.x*64 + wv*16;
  int bm = blockIdx.y*64;
  const ushort* Arow = A + (size_t)(br + u)*Kd + g4*8;
  f32x4 acc0 = {0,0,0,0}, acc1 = {0,0,0,0}, acc2 = {0,0,0,0}, acc3 = {0,0,0,0};
  for (int k0 = 0; k0 < Kd; k0 += 32) {
    s16x8 av = *(const s16x8*)(Arow + k0);
    s16x8 b0 = *(const s16x8*)(W + (size_t)(bm +  0 + u)*Kd + k0 + g4*8);
    s16x8 b1 = *(const s16x8*)(W + (size_t)(bm + 16 + u)*Kd + k0 + g4*8);
    s16x8 b2 = *(const s16x8*)(W + (size_t)(bm + 32 + u)*Kd + k0 + g4*8);
    s16x8 b3 = *(const s16x8*)(W + (size_t)(bm + 48 + u)*Kd + k0 + g4*8);
    acc0 = MFMA16(av, b0, acc0, 0,0,0);
    acc1 = MFMA16(av, b1, acc1, 0,0,0);
    acc2 = MFMA16(av, b2, acc2, 0,0,0);
    acc3 = MFMA16(av, b3, acc3, 0,0,0);
  }
  f32x4 ac[4] = {acc0, acc1, acc2, acc3};
  #pragma unroll
  for (int mt = 0; mt < 4; ++mt) {
    int col = bm + mt*16 + u;
    float b = bias ? bias[col] : 0.f;
    #pragma unroll
    for (int r = 0; r < 4; ++r) {
      float v = ac[mt][r] + b;
      if (RELU) v = fmaxf(v, 0.f);
      out[(size_t)(br + g4*4 + r)*ldo + col] = f2b(v);
    }
  }
}

// ---------- unified encoder (unchanged from round 12; 317us, spill-free) ----------
__global__ __launch_bounds__(512) __attribute__((amdgpu_waves_per_eu(2, 2))) void enc_all(
    const ushort* __restrict__ GiAll, const ushort* __restrict__ Wh,
    const float* __restrict__ bih, const float* __restrict__ bhh,
    float* __restrict__ Km, float* __restrict__ Cm, ushort* __restrict__ Bbf){
  __shared__ __align__(16) ushort hbf[2][80][EKSTR];
  __shared__ __align__(16) ushort gis[2][2][4][832];
  int tid = threadIdx.x, lane = tid & 63, wv = tid >> 6;
  int u = lane & 15, g4 = lane >> 4;
  int nb = blockIdx.x * 4;
  for (int i = tid; i < 2*80*EKSTR; i += 512) ((ushort*)hbf)[i] = 0;
  #pragma unroll
  for (int i0 = 0; i0 < 4; ++i0) {
    int i = tid + i0*512;
    if (i < 1664) {
      int flat = i*4;
      int fb = flat / 3328, rem = flat - fb*3328;
      int nl = rem / 832, k = rem - nl*832;
      int row = (nb+nl)*16 + (fb ? 15 : 0);
      *(us4*)&gis[0][fb][nl][k] = *(const us4*)(GiAll + (size_t)row*832 + k);
    }
  }
  BAR();
  int cur = 0;
  for (int j = 0; j < 16; ++j) {
    if (j < 15) {
      #pragma unroll
      for (int i0 = 0; i0 < 4; ++i0) {
        int i = tid + i0*512;
        if (i < 1664) {
          int flat = i*4;
          int fb = flat / 3328, rem = flat - fb*3328;
          int nl = rem / 832, k = rem - nl*832;
          int row = (nb+nl)*16 + (fb ? (14-j) : (j+1));
          *(us4*)&gis[cur^1][fb][nl][k] = *(const us4*)(GiAll + (size_t)row*832 + k);
        }
      }
    }
    #pragma unroll 1
    for (int tt = 0; tt < 2; ++tt) {
      int kt = 2*wv + tt;
      f32x4 acc[5][3];
      #pragma unroll
      for (int rt = 0; rt < 5; ++rt) {
        acc[rt][0] = (f32x4){0,0,0,0};
        acc[rt][1] = (f32x4){0,0,0,0};
        acc[rt][2] = (f32x4){0,0,0,0};
      }
      #pragma unroll
      for (int q = 0; q < 9; ++q) {
        int off = q*32 + g4*8;
        s16x8 w0 = *(const s16x8*)(Wh + (size_t)((3*kt+0)*16 + u)*288 + off);
        s16x8 w1 = *(const s16x8*)(Wh + (size_t)((3*kt+1)*16 + u)*288 + off);
        s16x8 w2 = *(const s16x8*)(Wh + (size_t)((3*kt+2)*16 + u)*288 + off);
        #pragma unroll
        for (int rt = 0; rt < 5; ++rt) {
          if (rt < 4 && rt*4 > j) continue;
          s16x8 av = *(const s16x8*)&hbf[cur][rt*16 + u][off];
          acc[rt][0] = MFMA16(av, w0, acc[rt][0], 0,0,0);
          acc[rt][1] = MFMA16(av, w1, acc[rt][1], 0,0,0);
          acc[rt][2] = MFMA16(av, w2, acc[rt][2], 0,0,0);
        }
      }
      int c = kt*16 + u;
      float bi0 = bih[c], bi1 = bih[257+c], bi2 = bih[514+c];
      float bh0 = bhh[c], bh1 = bhh[257+c], bh2 = bhh[514+c];
      float kmP[4] = {0.f, 0.f, 0.f, 0.f};
      #pragma unroll
      for (int rt = 0; rt < 4; ++rt) {
        int ii = rt*4 + g4;
        if (rt*4 <= j && ii <= j) {
          #pragma unroll
          for (int r = 0; r < 4; ++r) {
            int rowl = rt*16 + g4*4 + r;
            const ushort* gp = &gis[cur][0][r][3*kt*16];
            float hp = b2f(hbf[cur][rowl][c]);
            float h2 = gruh(b2f(gp[u]) + bi0, b2f(gp[16+u]) + bi1, b2f(gp[32+u]) + bi2,
                            acc[rt][0][r] + bh0, acc[rt][1][r] + bh1,
                            acc[rt][2][r] + bh2, hp);
            hbf[cur^1][rowl][c] = f2b(h2);
            kmP[r] += h2;
          }
        }
      }
      #pragma unroll
      for (int r = 0; r < 4; ++r) {
        float s = kmP[r];
        s += __shfl_xor(s, 16, 64);
        s += __shfl_xor(s, 32, 64);
        if (g4 == 0) Km[((size_t)(nb+r)*16 + j)*256 + c] = s;
      }
      if (g4 == 0) {
        #pragma unroll
        for (int r = 0; r < 4; ++r) {
          const ushort* gp = &gis[cur][1][r][3*kt*16];
          float hp = b2f(hbf[cur][64 + r][c]);
          float h2 = gruh(b2f(gp[u]) + bi0, b2f(gp[16+u]) + bi1, b2f(gp[32+u]) + bi2,
                          acc[4][0][r] + bh0, acc[4][1][r] + bh1,
                          acc[4][2][r] + bh2, hp);
          hbf[cur^1][64 + r][c] = f2b(h2);
          Bbf[((size_t)j*1024 + nb + r)*288 + c] = f2b(h2);
        }
      }
    }
    if (wv < 5) {
      int rt = wv;
      bool go = (rt == 4) || (rt*4 <= j);
      if (go) {
        f32x4 a0 = {0,0,0,0}, a1 = {0,0,0,0}, a2 = {0,0,0,0};
        #pragma unroll
        for (int q = 0; q < 9; ++q) {
          int off = q*32 + g4*8;
          s16x8 w0 = *(const s16x8*)(Wh + (size_t)(48*16 + u)*288 + off);
          s16x8 w1 = *(const s16x8*)(Wh + (size_t)(49*16 + u)*288 + off);
          s16x8 w2 = *(const s16x8*)(Wh + (size_t)(50*16 + u)*288 + off);
          s16x8 av = *(const s16x8*)&hbf[cur][rt*16 + u][off];
          a0 = MFMA16(av, w0, a0, 0,0,0);
          a1 = MFMA16(av, w1, a1, 0,0,0);
          a2 = MFMA16(av, w2, a2, 0,0,0);
        }
        if (u == 0) {
          float bi0 = bih[256], bi1 = bih[513], bi2 = bih[770];
          float bh0 = bhh[256], bh1 = bhh[513], bh2 = bhh[770];
          if (rt < 4) {
            int ii = rt*4 + g4;
            if (ii <= j) {
              #pragma unroll
              for (int r = 0; r < 4; ++r) {
                int rowl = rt*16 + g4*4 + r;
                const ushort* gp = &gis[cur][0][r][768];
                float hp = b2f(hbf[cur][rowl][256]);
                float h2 = gruh(b2f(gp[0]) + bi0, b2f(gp[16]) + bi1, b2f(gp[32]) + bi2,
                                a0[r] + bh0, a1[r] + bh1, a2[r] + bh2, hp);
                hbf[cur^1][rowl][256] = f2b(h2);
                Cm[(size_t)(nb+r)*256 + ii*16 + j] = h2;
              }
            }
          } else if (g4 == 0) {
            #pragma unroll
            for (int r = 0; r < 4; ++r) {
              const ushort* gp = &gis[cur][1][r][768];
              float hp = b2f(hbf[cur][64 + r][256]);
              float h2 = gruh(b2f(gp[0]) + bi0, b2f(gp[16]) + bi1, b2f(gp[32]) + bi2,
                              a0[r] + bh0, a1[r] + bh1, a2[r] + bh2, hp);
              hbf[cur^1][64 + r][256] = f2b(h2);
              Bbf[((size_t)j*1024 + nb + r)*288 + 256] = f2b(h2);
            }
          }
        }
      }
    }
    BAR();
    cur ^= 1;
  }
}

// ---------- fused backward-K accumulate + Kmbf + C fill + wb dot ----------
__global__ void accum_wb(const ushort* __restrict__ Bbf, const float* __restrict__ Km,
                         ushort* __restrict__ Kmbf, float* __restrict__ Cm,
                         const float* __restrict__ ba, float* __restrict__ wbv){
  __shared__ float kms[16][257];
  int n = blockIdx.x, c = threadIdx.x;
  float s = 0.f;
  for (int jj = 15; jj >= 0; --jj) {
    if (jj < 15) s += b2f(Bbf[((size_t)(14-jj)*1024 + n)*288 + c]);
    size_t o = ((size_t)n*16 + jj)*256 + c;
    float v = Km[o] + s;
    Kmbf[o] = f2b(v);
    kms[jj][c] = v;
  }
  int i = c >> 4, j = c & 15;
  if (i > j) Cm[(size_t)n*256 + i*16 + j] = b2f(Bbf[((size_t)(i-1-j)*1024 + n)*288 + 256]);
  __syncthreads();
  int l = c >> 4, lane16 = c & 15;
  float t = 0.f;
  for (int m = lane16; m < 256; m += 16) t += kms[l][m]*ba[m];
  t += __shfl_down(t, 8, 16); t += __shfl_down(t, 4, 16);
  t += __shfl_down(t, 2, 16); t += __shfl_down(t, 1, 16);
  if (lane16 == 0) wbv[n*16 + l] = t;
}

// ---------- phase 4: whole T loop, gi computed in-lane per step (no Gi buffers) ----------
// 64 blocks x 8 waves; wave owns col-tiles kt, kt+8. Per step per tile:
//   gi = x2 @ Wi^T (MFMA; D-layout == gate lane layout -> gi never leaves the lane),
//   gh = h @ Wh^T (Wh preloaded, 192 VGPR), gates, LDS h double-buffer, 1 lgkm barrier.
// hcT does NOT alias x2 (moved), so no intra-step RAW hazard on x2.
__global__ __launch_bounds__(512) __attribute__((amdgpu_waves_per_eu(2, 2))) void cell_all(
    const ushort* __restrict__ x2, const ushort* __restrict__ Wi, const ushort* __restrict__ Wh,
    const float* __restrict__ cb, const float* __restrict__ bhh, const float* __restrict__ hbuf,
    ushort* __restrict__ hcT, float* __restrict__ out){
  __shared__ __align__(16) ushort hbf[2][16][266];
  int tid = threadIdx.x, lane = tid & 63, wv = tid >> 6;
  int u = lane & 15, g4 = lane >> 4;
  int n0 = blockIdx.x * 16;
  int ktA = wv, ktB = wv + 8;
  int cA = ktA*16 + u, cB = ktB*16 + u;
  s16x8 WA0[8], WA1[8], WA2[8], WB0[8], WB1[8], WB2[8];
  #pragma unroll
  for (int q = 0; q < 8; ++q) {
    int off = q*32 + g4*8;
    WA0[q] = *(const s16x8*)(Wh + (size_t)((3*ktA+0)*16 + u)*256 + off);
    WA1[q] = *(const s16x8*)(Wh + (size_t)((3*ktA+1)*16 + u)*256 + off);
    WA2[q] = *(const s16x8*)(Wh + (size_t)((3*ktA+2)*16 + u)*256 + off);
    WB0[q] = *(const s16x8*)(Wh + (size_t)((3*ktB+0)*16 + u)*256 + off);
    WB1[q] = *(const s16x8*)(Wh + (size_t)((3*ktB+1)*16 + u)*256 + off);
    WB2[q] = *(const s16x8*)(Wh + (size_t)((3*ktB+2)*16 + u)*256 + off);
  }
  float cbA0 = cb[(3*ktA+0)*16 + u], cbA1 = cb[(3*ktA+1)*16 + u], cbA2 = cb[(3*ktA+2)*16 + u];
  float cbB0 = cb[(3*ktB+0)*16 + u], cbB1 = cb[(3*ktB+1)*16 + u], cbB2 = cb[(3*ktB+2)*16 + u];
  float bhgA = bhh[512 + cA], bhgB = bhh[512 + cB];
  for (int i = tid; i < 16*256; i += 512) {
    int rr = i >> 8, cc = i & 255;
    hbf[0][rr][cc] = f2b(hbuf[(size_t)(n0 + rr)*256 + cc]);
  }
  BAR();
  int cur = 0;
  for (int t = 0; t < 64; ++t) {
    const ushort* xr = x2 + ((size_t)t*1024 + n0 + u)*256 + g4*8;
    // ---- tile A ----
    {
      f32x4 g0={0,0,0,0}, g1={0,0,0,0}, g2={0,0,0,0};
      #pragma unroll
      for (int q = 0; q < 8; ++q) {
        int off = q*32 + g4*8;
        s16x8 av = *(const s16x8*)(xr + q*32);
        s16x8 w0 = *(const s16x8*)(Wi + (size_t)((3*ktA+0)*16 + u)*256 + off);
        s16x8 w1 = *(const s16x8*)(Wi + (size_t)((3*ktA+1)*16 + u)*256 + off);
        s16x8 w2 = *(const s16x8*)(Wi + (size_t)((3*ktA+2)*16 + u)*256 + off);
        g0 = MFMA16(av, w0, g0, 0,0,0);
        g1 = MFMA16(av, w1, g1, 0,0,0);
        g2 = MFMA16(av, w2, g2, 0,0,0);
      }
      f32x4 a0={0,0,0,0}, a1={0,0,0,0}, a2={0,0,0,0};
      #pragma unroll
      for (int q = 0; q < 8; ++q) {
        s16x8 ah = *(const s16x8*)&hbf[cur][u][q*32 + g4*8];
        a0 = MFMA16(ah, WA0[q], a0, 0,0,0);
        a1 = MFMA16(ah, WA1[q], a1, 0,0,0);
        a2 = MFMA16(ah, WA2[q], a2, 0,0,0);
      }
      #pragma unroll
      for (int r = 0; r < 4; ++r) {
        int row = g4*4 + r;
        float hp = b2f(hbf[cur][row][cA]);
        float rr2 = 1.f/(1.f + __expf(-(g0[r] + cbA0 + a0[r])));
        float zz  = 1.f/(1.f + __expf(-(g1[r] + cbA1 + a1[r])));
        float ex  = __expf(2.f*(g2[r] + cbA2 + rr2*(a2[r] + bhgA)));
        float gg  = 1.f - 2.f/(ex + 1.f);
        float h2  = (1.f - zz)*gg + zz*hp;
        ushort hb = f2b(h2);
        hbf[cur^1][row][cA] = hb;
        hcT[((size_t)t*1024 + n0 + row)*256 + cA] = hb;
        out[((size_t)t*1024 + n0 + row)*STATE_ + 2 + cA] = h2;
        if (t == 63) out[((size_t)64*1024 + n0 + row)*STATE_ + 2 + cA] = h2;
      }
    }
    // ---- tile B ----
    {
      f32x4 g0={0,0,0,0}, g1={0,0,0,0}, g2={0,0,0,0};
      #pragma unroll
      for (int q = 0; q < 8; ++q) {
        int off = q*32 + g4*8;
        s16x8 av = *(const s16x8*)(xr + q*32);
        s16x8 w0 = *(const s16x8*)(Wi + (size_t)((3*ktB+0)*16 + u)*256 + off);
        s16x8 w1 = *(const s16x8*)(Wi + (size_t)((3*ktB+1)*16 + u)*256 + off);
        s16x8 w2 = *(const s16x8*)(Wi + (size_t)((3*ktB+2)*16 + u)*256 + off);
        g0 = MFMA16(av, w0, g0, 0,0,0);
        g1 = MFMA16(av, w1, g1, 0,0,0);
        g2 = MFMA16(av, w2, g2, 0,0,0);
      }
      f32x4 b0={0,0,0,0}, b1={0,0,0,0}, b2={0,0,0,0};
      #pragma unroll
      for (int q = 0; q < 8; ++q) {
        s16x8 ah = *(const s16x8*)&hbf[cur][u][q*32 + g4*8];
        b0 = MFMA16(ah, WB0[q], b0, 0,0,0);
        b1 = MFMA16(ah, WB1[q], b1, 0,0,0);
        b2 = MFMA16(ah, WB2[q], b2, 0,0,0);
      }
      #pragma unroll
      for (int r = 0; r < 4; ++r) {
        int row = g4*4 + r;
        float hp = b2f(hbf[cur][row][cB]);
        float rr2 = 1.f/(1.f + __expf(-(g0[r] + cbB0 + b0[r])));
        float zz  = 1.f/(1.f + __expf(-(g1[r] + cbB1 + b1[r])));
        float ex  = __expf(2.f*(g2[r] + cbB2 + rr2*(b2[r] + bhgB)));
        float gg  = 1.f - 2.f/(ex + 1.f);
        float h2  = (1.f - zz)*gg + zz*hp;
        ushort hb = f2b(h2);
        hbf[cur^1][row][cB] = hb;
        hcT[((size_t)t*1024 + n0 + row)*256 + cB] = hb;
        out[((size_t)t*1024 + n0 + row)*STATE_ + 2 + cB] = h2;
        if (t == 63) out[((size_t)64*1024 + n0 + row)*STATE_ + 2 + cB] = h2;
      }
    }
    BAR();
    cur ^= 1;
  }
}

// ---------- attention/softmax + a,v columns (v_out merged in) ----------
__global__ __launch_bounds__(256) void attn_v(
    const ushort* __restrict__ Ktl, const ushort* __restrict__ hcT,
    const float* __restrict__ wbv, const float* __restrict__ Cm,
    const float* __restrict__ p0, const int* __restrict__ act,
    const float* __restrict__ Wc, const float* __restrict__ bc,
    float* __restrict__ out){
  __shared__ float WcS[256];
  int n = blockIdx.x;
  int tid = threadIdx.x;
  WcS[tid] = Wc[tid];
  __syncthreads();
  int lane = tid & 63, wv = tid >> 6;
  int u = lane & 15, g4 = lane >> 4;
  int t0 = wv*16;
  const ushort* Ka = Ktl + ((size_t)n*16 + u)*256 + g4*8;
  const ushort* Hb = hcT + ((size_t)(t0 + u)*1024 + n)*256 + g4*8;
  f32x4 acc = {0,0,0,0};
  float vp = 0.f;
  #pragma unroll
  for (int q = 0; q < 8; ++q) {
    s16x8 av = *(const s16x8*)(Ka + q*32);
    s16x8 bv = *(const s16x8*)(Hb + q*32);
    acc = MFMA16(av, bv, acc, 0,0,0);
    #pragma unroll
    for (int j = 0; j < 8; ++j) vp += b2f((ushort)bv[j]) * WcS[q*32 + g4*8 + j];
  }
  vp += __shfl_xor(vp, 16, 64);
  vp += __shfl_xor(vp, 32, 64);
  float vfin = vp + bc[0];
  int t = t0 + u;
  float ps[4];
  if (t == 0) {
    #pragma unroll
    for (int r = 0; r < 4; ++r) {
      float catt = 0.f;
      for (int i = 0; i < 16; ++i) catt += p0[n*16 + i]*Cm[(size_t)n*256 + i*16 + g4*4 + r];
      ps[r] = (acc[r] + wbv[n*16 + g4*4 + r]) * catt;
    }
  } else {
    int ap = act[(size_t)(t-1)*1024 + n];
    #pragma unroll
    for (int r = 0; r < 4; ++r)
      ps[r] = (acc[r] + wbv[n*16 + g4*4 + r]) * Cm[(size_t)n*256 + ap*16 + g4*4 + r];
  }
  float mx = fmaxf(fmaxf(ps[0], ps[1]), fmaxf(ps[2], ps[3]));
  mx = fmaxf(mx, __shfl_xor(mx, 16, 64));
  mx = fmaxf(mx, __shfl_xor(mx, 32, 64));
  float e[4], se = 0.f;
  #pragma unroll
  for (int r = 0; r < 4; ++r) { e[r] = __expf(ps[r] - mx); se += e[r]; }
  se += __shfl_xor(se, 16, 64);
  se += __shfl_xor(se, 32, 64);
  float inv = 1.f/se;
  int a = act[(size_t)t*1024 + n];
  size_t ro = ((size_t)t*1024 + n)*STATE_;
  if (g4 == 0) { out[ro] = (float)a; out[ro + 1] = vfin; }
  #pragma unroll
  for (int r = 0; r < 4; ++r) {
    out[ro + 258 + g4*4 + r] = e[r]*inv;
    out[ro + 274 + g4*4 + r] = (g4*4 + r == a) ? 1.f : 0.f;
  }
  if (t == 63) {
    size_t r2 = ((size_t)64*1024 + n)*STATE_;
    if (g4 == 0) { out[r2] = (float)a; out[r2 + 1] = vfin; }
    #pragma unroll
    for (int r = 0; r < 4; ++r) {
      out[r2 + 258 + g4*4 + r] = e[r]*inv;
      out[r2 + 274 + g4*4 + r] = (g4*4 + r == a) ? 1.f : 0.f;
    }
  }
}

extern "C" void kernel_launch(void* const* d_in, const int* in_sizes, int n_in,
                              void* d_out, int out_size, void* d_ws, size_t ws_size,
                              hipStream_t stream){
  (void)in_sizes; (void)n_in; (void)out_size; (void)ws_size;
  const float* cond  = (const float*)d_in[0];
  const int*   lines = (const int*)  d_in[1];
  const int*   act   = (const int*)  d_in[2];
  const float* hxs   = (const float*)d_in[3];
  const float* emb   = (const float*)d_in[4];
  const float* wih_e = (const float*)d_in[5];
  const float* whh_e = (const float*)d_in[6];
  const float* bih_e = (const float*)d_in[7];
  const float* bhh_e = (const float*)d_in[8];
  const float* W1    = (const float*)d_in[9];
  const float* b1    = (const float*)d_in[10];
  const float* W2    = (const float*)d_in[11];
  const float* b2    = (const float*)d_in[12];
  const float* wih_c = (const float*)d_in[13];
  const float* whh_c = (const float*)d_in[14];
  const float* bih_c = (const float*)d_in[15];
  const float* bhh_c = (const float*)d_in[16];
  const float* Wa    = (const float*)d_in[17];
  const float* ba    = (const float*)d_in[18];
  const float* Wc    = (const float*)d_in[19];
  const float* bc    = (const float*)d_in[20];
  float* out = (float*)d_out;

  char* base = (char*)d_ws;
  ushort* Mbf    = (ushort*)(base + 0);             // [16384,256]       P0-P3
  ushort* Bbf    = (ushort*)(base + 8388608);       // [16,1024,288]     P1-P2
  float*  Km     = (float*) (base + 17825792);      // [16384,256] f32   P1-P2
  ushort* Kmbf   = (ushort*)(base + 34603008);      // [16384,256]       P2
  ushort* xcat   = (ushort*)(base + 8388608);       // [65536,320]       P3 (over Bbf/Km/Kmbf)
  ushort* x2     = (ushort*)(base + 8388608);       // [65536,256]       P3-P4 (over xcat)
  ushort* GiAll  = (ushort*)(base + 50331648);      // [16384,832]       P1
  ushort* x1     = (ushort*)(base + 50331648);      // [65536,256]       P3 (over GiAll)
  ushort* hcT    = (ushort*)(base + 50331648);      // [64,1024,256]     P4-P5 (over x1; NOT x2!)
  ushort* Ktl    = (ushort*)(base + 100663296);     // [16384,256]       P2-P5
  float*  Cm     = (float*) (base + 109051904);     // [1024,16,16]
  float*  hbuf   = (float*) (base + 110100480);     // [1024,256]
  float*  p0     = (float*) (base + 111149056);     // [1024,16]
  float*  r0v    = (float*) (base + 111214592);     // [1024,256]
  float*  wbv    = (float*) (base + 112263168);     // [1024,16]
  ushort* wihe_p = (ushort*)(base + 112328704);     // [832,256]
  ushort* whhe_p = (ushort*)(base + 112754688);     // [832,288]
  ushort* wihc_p = (ushort*)(base + 113233920);     // [768,256]
  ushort* whhc_p = (ushort*)(base + 113627136);     // [768,256]
  ushort* W1b    = (ushort*)(base + 114020352);     // [256,320]
  ushort* W2b    = (ushort*)(base + 114184192);     // [256,256]
  ushort* WaTb   = (ushort*)(base + 114315264);     // [256,256]
  float*  cbias  = (float*) (base + 114446336);     // [768]

  prep_all<<<4139, 256, 0, stream>>>(wih_e, whh_e, wihe_p, whhe_p,
                                     wih_c, whh_c, wihc_p, whhc_p,
                                     bih_c, bhh_c, cbias, W1, W1b, W2, W2b, Wa, WaTb);
  emb_init_r0<<<1024, 256, 0, stream>>>(lines, emb, hxs, Mbf, hbuf, p0, r0v);

  gemm_mfma<0><<<dim3(256, 13), 256, 0, stream>>>(Mbf, wihe_p, nullptr, GiAll, 256, 832);
  enc_all<<<256, 512, 0, stream>>>(GiAll, whhe_p, bih_e, bhh_e, Km, Cm, Bbf);
  accum_wb<<<1024, 256, 0, stream>>>(Bbf, Km, Kmbf, Cm, ba, wbv);
  gemm_mfma<0><<<dim3(256, 4), 256, 0, stream>>>(Kmbf, WaTb, nullptr, Ktl, 256, 256);

  build_xcat8<<<10240, 256, 0, stream>>>(cond, act, r0v, Mbf, xcat);
  gemm_mfma<1><<<dim3(1024, 4), 256, 0, stream>>>(xcat, W1b, b1, x1, 320, 256);
  gemm_mfma<1><<<dim3(1024, 4), 256, 0, stream>>>(x1, W2b, b2, x2, 256, 256);

  cell_all<<<64, 512, 0, stream>>>(x2, wihc_p, whhc_p, cbias, bhh_c, hbuf, hcT, out);

  attn_v<<<1024, 256, 0, stream>>>(Ktl, hcT, wbv, Cm, p0, act, Wc, bc, out);
}

// Round 14
// 1184.874 us; speedup vs baseline: 1.4618x; 1.4618x over previous
//
#include <hip/hip_runtime.h>
#include <hip/hip_bf16.h>
#include <cstddef>

#define T_ 64
#define N_ 1024
#define L_ 16
#define H_ 256
#define STATE_ 290
#define EKSTR 296   // enc hbf row stride (ushorts): 592B = 37*16, b128-aligned

typedef short s16x8 __attribute__((ext_vector_type(8)));
typedef float f32x4 __attribute__((ext_vector_type(4)));
typedef ushort us4 __attribute__((ext_vector_type(4)));
typedef ushort us8 __attribute__((ext_vector_type(8)));
#define MFMA16 __builtin_amdgcn_mfma_f32_16x16x32_bf16

// raw barrier: wait LDS ops only, do NOT drain global stores.
#define BAR() asm volatile("s_waitcnt lgkmcnt(0)\n\ts_barrier" ::: "memory")

__device__ __forceinline__ float b2f(ushort u){ return __uint_as_float(((unsigned)u) << 16); }
__device__ __forceinline__ ushort f2b(float f){
  unsigned x = __float_as_uint(f);
  return (ushort)((x + 0x7FFFu + ((x >> 16) & 1u)) >> 16);
}
__device__ __forceinline__ float gruh(float gir,float giz,float gig,
                                      float ghr,float ghz,float ghg,float hp){
  float r = 1.f/(1.f + __expf(-(gir + ghr)));
  float z = 1.f/(1.f + __expf(-(giz + ghz)));
  float g = tanhf(gig + r*ghg);
  return (1.f - z)*g + z*hp;
}

// ---------- fused weight prep: all permutes/converts in ONE launch ----------
__global__ void prep_all(
    const float* __restrict__ wih_e, const float* __restrict__ whh_e,
    ushort* __restrict__ wihe_p, ushort* __restrict__ whhe_p,
    const float* __restrict__ wih_c, const float* __restrict__ whh_c,
    ushort* __restrict__ wihc_p, ushort* __restrict__ whhc_p,
    const float* __restrict__ bih_c, const float* __restrict__ bhh_c, float* __restrict__ cb,
    const float* __restrict__ W1, ushort* __restrict__ W1b,
    const float* __restrict__ W2, ushort* __restrict__ W2b,
    const float* __restrict__ Wa, ushort* __restrict__ WaTb){
  int b = blockIdx.x, t = threadIdx.x;
  if (b < 832) {                       // perm wih_e [771,256] -> [832,256]
    int idx = b*256 + t;
    int d = idx >> 8, c = idx & 255;
    int tile = d >> 4, uu = d & 15;
    int k = tile/3, p = tile - 3*k;
    int hc = k*16 + uu;
    bool ok = (tile < 51) && (hc < 257);
    wihe_p[idx] = ok ? f2b(wih_e[(size_t)(p*257 + hc)*256 + c]) : (ushort)0;
  } else if (b < 1768) {               // perm whh_e [771,257] -> [832,288]
    int idx = (b-832)*256 + t;
    int d = idx / 288, c = idx - d*288;
    int tile = d >> 4, uu = d & 15;
    int k = tile/3, p = tile - 3*k;
    int hc = k*16 + uu;
    bool ok = (tile < 51) && (hc < 257) && (c < 257);
    whhe_p[idx] = ok ? f2b(whh_e[(size_t)(p*257 + hc)*257 + c]) : (ushort)0;
  } else if (b < 2536) {               // perm wih_c [768,256]
    int idx = (b-1768)*256 + t;
    int d = idx >> 8, c = idx & 255;
    int tile = d >> 4, uu = d & 15;
    int k = tile/3, p = tile - 3*k;
    wihc_p[idx] = f2b(wih_c[(size_t)(p*256 + k*16 + uu)*256 + c]);
  } else if (b < 3304) {               // perm whh_c [768,256]
    int idx = (b-2536)*256 + t;
    int d = idx >> 8, c = idx & 255;
    int tile = d >> 4, uu = d & 15;
    int k = tile/3, p = tile - 3*k;
    whhc_p[idx] = f2b(whh_c[(size_t)(p*256 + k*16 + uu)*256 + c]);
  } else if (b < 3307) {               // cbias (r,z: bih+bhh; g: bih)
    int d = (b-3304)*256 + t;
    if (d < 768) {
      int tile = d >> 4, uu = d & 15;
      int k = tile/3, p = tile - 3*k;
      int src = p*256 + k*16 + uu;
      cb[d] = bih_c[src] + (p < 2 ? bhh_c[src] : 0.f);
    }
  } else if (b < 3627) {               // W1 convert [256,320]
    int idx = (b-3307)*256 + t;
    W1b[idx] = f2b(W1[idx]);
  } else if (b < 3883) {               // W2 convert [256,256]
    int idx = (b-3627)*256 + t;
    W2b[idx] = f2b(W2[idx]);
  } else {                             // Wa transpose -> bf16
    int m = b - 3883;
    WaTb[(size_t)t*256 + m] = f2b(Wa[(size_t)m*256 + t]);
  }
}

// ---------- fused embed + init_state + r0 ----------
__global__ void emb_init_r0(
    const int* __restrict__ lines, const float* __restrict__ emb, const float* __restrict__ hxs,
    ushort* __restrict__ Mbf, float* __restrict__ hbuf, float* __restrict__ p0,
    float* __restrict__ r0v){
  __shared__ ushort Ms[16][256];
  __shared__ float p0s[16];
  __shared__ int ls[16];
  __shared__ int nz;
  int n = blockIdx.x, t = threadIdx.x;
  if (t == 0) nz = 0;
  if (t < 16) ls[t] = lines[n*16 + t];
  __syncthreads();
  #pragma unroll
  for (int l = 0; l < 16; ++l) {
    ushort v = f2b(emb[(size_t)ls[l]*256 + t]);
    Ms[l][t] = v;
    Mbf[((size_t)n*16 + l)*256 + t] = v;
  }
  for (int c = t; c < STATE_; c += 256)
    if (hxs[(size_t)n*STATE_ + c] != 0.f) atomicOr(&nz, 1);
  __syncthreads();
  bool new_ep = (nz == 0);
  hbuf[(size_t)n*256 + t] = hxs[(size_t)n*STATE_ + 2 + t];
  if (t < 16) {
    float pv = hxs[(size_t)n*STATE_ + 2 + 256 + 16 + t];
    if (t == 0 && new_ep) pv = 1.f;
    p0[n*16 + t] = pv;
    p0s[t] = pv;
  }
  __syncthreads();
  float s = 0.f;
  #pragma unroll
  for (int l = 0; l < 16; ++l) s += p0s[l]*b2f(Ms[l][t]);
  r0v[(size_t)n*256 + t] = s;
}

__global__ void build_xcat8(const float* __restrict__ cond, const int* __restrict__ act,
                            const float* __restrict__ r0v, const ushort* __restrict__ Mbf,
                            ushort* __restrict__ xcat){
  int idx = blockIdx.x*256 + threadIdx.x;
  if (idx >= T_*N_*40) return;
  int kc = idx % 40;
  int row = idx / 40;
  int n = row & 1023, t = row >> 10;
  us8 v;
  if (kc < 8) {
    const float* cp = cond + (size_t)row*64 + kc*8;
    #pragma unroll
    for (int i = 0; i < 8; ++i) v[i] = f2b(cp[i]);
  } else if (t == 0) {
    const float* rp = r0v + (size_t)n*256 + (kc-8)*8;
    #pragma unroll
    for (int i = 0; i < 8; ++i) v[i] = f2b(rp[i]);
  } else {
    int a = act[(size_t)(t-1)*1024 + n];
    v = *(const us8*)(Mbf + ((size_t)n*16 + a)*256 + (kc-8)*8);
  }
  *(us8*)(xcat + (size_t)idx*8) = v;
}

// ---------- MFMA GEMM: out[r,col] = act(sum_k A[r,k]*W[col,k] + bias[col]), bf16 out ----------
template<int RELU>
__global__ __launch_bounds__(256) void gemm_mfma(
    const ushort* __restrict__ A, const ushort* __restrict__ W,
    const float* __restrict__ bias, ushort* __restrict__ out,
    int Kd, int ldo){
  int lane = threadIdx.x & 63, wv = threadIdx.x >> 6;
  int u = lane & 15, g4 = lane >> 4;
  int br = blockIdx.x*64 + wv*16;
  int bm = blockIdx.y*64;
  const ushort* Arow = A + (size_t)(br + u)*Kd + g4*8;
  f32x4 acc0 = {0,0,0,0}, acc1 = {0,0,0,0}, acc2 = {0,0,0,0}, acc3 = {0,0,0,0};
  for (int k0 = 0; k0 < Kd; k0 += 32) {
    s16x8 av = *(const s16x8*)(Arow + k0);
    s16x8 b0 = *(const s16x8*)(W + (size_t)(bm +  0 + u)*Kd + k0 + g4*8);
    s16x8 b1 = *(const s16x8*)(W + (size_t)(bm + 16 + u)*Kd + k0 + g4*8);
    s16x8 b2 = *(const s16x8*)(W + (size_t)(bm + 32 + u)*Kd + k0 + g4*8);
    s16x8 b3 = *(const s16x8*)(W + (size_t)(bm + 48 + u)*Kd + k0 + g4*8);
    acc0 = MFMA16(av, b0, acc0, 0,0,0);
    acc1 = MFMA16(av, b1, acc1, 0,0,0);
    acc2 = MFMA16(av, b2, acc2, 0,0,0);
    acc3 = MFMA16(av, b3, acc3, 0,0,0);
  }
  f32x4 ac[4] = {acc0, acc1, acc2, acc3};
  #pragma unroll
  for (int mt = 0; mt < 4; ++mt) {
    int col = bm + mt*16 + u;
    float b = bias ? bias[col] : 0.f;
    #pragma unroll
    for (int r = 0; r < 4; ++r) {
      float v = ac[mt][r] + b;
      if (RELU) v = fmaxf(v, 0.f);
      out[(size_t)(br + g4*4 + r)*ldo + col] = f2b(v);
    }
  }
}

// ---------- unified encoder (round-12 proven: 317us, spill-free, VGPR 100) ----------
__global__ __launch_bounds__(512) __attribute__((amdgpu_waves_per_eu(2, 2))) void enc_all(
    const ushort* __restrict__ GiAll, const ushort* __restrict__ Wh,
    const float* __restrict__ bih, const float* __restrict__ bhh,
    float* __restrict__ Km, float* __restrict__ Cm, ushort* __restrict__ Bbf){
  __shared__ __align__(16) ushort hbf[2][80][EKSTR];
  __shared__ __align__(16) ushort gis[2][2][4][832];
  int tid = threadIdx.x, lane = tid & 63, wv = tid >> 6;
  int u = lane & 15, g4 = lane >> 4;
  int nb = blockIdx.x * 4;
  for (int i = tid; i < 2*80*EKSTR; i += 512) ((ushort*)hbf)[i] = 0;
  #pragma unroll
  for (int i0 = 0; i0 < 4; ++i0) {
    int i = tid + i0*512;
    if (i < 1664) {
      int flat = i*4;
      int fb = flat / 3328, rem = flat - fb*3328;
      int nl = rem / 832, k = rem - nl*832;
      int row = (nb+nl)*16 + (fb ? 15 : 0);
      *(us4*)&gis[0][fb][nl][k] = *(const us4*)(GiAll + (size_t)row*832 + k);
    }
  }
  BAR();
  int cur = 0;
  for (int j = 0; j < 16; ++j) {
    if (j < 15) {
      #pragma unroll
      for (int i0 = 0; i0 < 4; ++i0) {
        int i = tid + i0*512;
        if (i < 1664) {
          int flat = i*4;
          int fb = flat / 3328, rem = flat - fb*3328;
          int nl = rem / 832, k = rem - nl*832;
          int row = (nb+nl)*16 + (fb ? (14-j) : (j+1));
          *(us4*)&gis[cur^1][fb][nl][k] = *(const us4*)(GiAll + (size_t)row*832 + k);
        }
      }
    }
    #pragma unroll 1
    for (int tt = 0; tt < 2; ++tt) {
      int kt = 2*wv + tt;
      f32x4 acc[5][3];
      #pragma unroll
      for (int rt = 0; rt < 5; ++rt) {
        acc[rt][0] = (f32x4){0,0,0,0};
        acc[rt][1] = (f32x4){0,0,0,0};
        acc[rt][2] = (f32x4){0,0,0,0};
      }
      #pragma unroll
      for (int q = 0; q < 9; ++q) {
        int off = q*32 + g4*8;
        s16x8 w0 = *(const s16x8*)(Wh + (size_t)((3*kt+0)*16 + u)*288 + off);
        s16x8 w1 = *(const s16x8*)(Wh + (size_t)((3*kt+1)*16 + u)*288 + off);
        s16x8 w2 = *(const s16x8*)(Wh + (size_t)((3*kt+2)*16 + u)*288 + off);
        #pragma unroll
        for (int rt = 0; rt < 5; ++rt) {
          if (rt < 4 && rt*4 > j) continue;
          s16x8 av = *(const s16x8*)&hbf[cur][rt*16 + u][off];
          acc[rt][0] = MFMA16(av, w0, acc[rt][0], 0,0,0);
          acc[rt][1] = MFMA16(av, w1, acc[rt][1], 0,0,0);
          acc[rt][2] = MFMA16(av, w2, acc[rt][2], 0,0,0);
        }
      }
      int c = kt*16 + u;
      float bi0 = bih[c], bi1 = bih[257+c], bi2 = bih[514+c];
      float bh0 = bhh[c], bh1 = bhh[257+c], bh2 = bhh[514+c];
      float kmP[4] = {0.f, 0.f, 0.f, 0.f};
      #pragma unroll
      for (int rt = 0; rt < 4; ++rt) {
        int ii = rt*4 + g4;
        if (rt*4 <= j && ii <= j) {
          #pragma unroll
          for (int r = 0; r < 4; ++r) {
            int rowl = rt*16 + g4*4 + r;
            const ushort* gp = &gis[cur][0][r][3*kt*16];
            float hp = b2f(hbf[cur][rowl][c]);
            float h2 = gruh(b2f(gp[u]) + bi0, b2f(gp[16+u]) + bi1, b2f(gp[32+u]) + bi2,
                            acc[rt][0][r] + bh0, acc[rt][1][r] + bh1,
                            acc[rt][2][r] + bh2, hp);
            hbf[cur^1][rowl][c] = f2b(h2);
            kmP[r] += h2;
          }
        }
      }
      #pragma unroll
      for (int r = 0; r < 4; ++r) {
        float s = kmP[r];
        s += __shfl_xor(s, 16, 64);
        s += __shfl_xor(s, 32, 64);
        if (g4 == 0) Km[((size_t)(nb+r)*16 + j)*256 + c] = s;
      }
      if (g4 == 0) {
        #pragma unroll
        for (int r = 0; r < 4; ++r) {
          const ushort* gp = &gis[cur][1][r][3*kt*16];
          float hp = b2f(hbf[cur][64 + r][c]);
          float h2 = gruh(b2f(gp[u]) + bi0, b2f(gp[16+u]) + bi1, b2f(gp[32+u]) + bi2,
                          acc[4][0][r] + bh0, acc[4][1][r] + bh1,
                          acc[4][2][r] + bh2, hp);
          hbf[cur^1][64 + r][c] = f2b(h2);
          Bbf[((size_t)j*1024 + nb + r)*288 + c] = f2b(h2);
        }
      }
    }
    if (wv < 5) {
      int rt = wv;
      bool go = (rt == 4) || (rt*4 <= j);
      if (go) {
        f32x4 a0 = {0,0,0,0}, a1 = {0,0,0,0}, a2 = {0,0,0,0};
        #pragma unroll
        for (int q = 0; q < 9; ++q) {
          int off = q*32 + g4*8;
          s16x8 w0 = *(const s16x8*)(Wh + (size_t)(48*16 + u)*288 + off);
          s16x8 w1 = *(const s16x8*)(Wh + (size_t)(49*16 + u)*288 + off);
          s16x8 w2 = *(const s16x8*)(Wh + (size_t)(50*16 + u)*288 + off);
          s16x8 av = *(const s16x8*)&hbf[cur][rt*16 + u][off];
          a0 = MFMA16(av, w0, a0, 0,0,0);
          a1 = MFMA16(av, w1, a1, 0,0,0);
          a2 = MFMA16(av, w2, a2, 0,0,0);
        }
        if (u == 0) {
          float bi0 = bih[256], bi1 = bih[513], bi2 = bih[770];
          float bh0 = bhh[256], bh1 = bhh[513], bh2 = bhh[770];
          if (rt < 4) {
            int ii = rt*4 + g4;
            if (ii <= j) {
              #pragma unroll
              for (int r = 0; r < 4; ++r) {
                int rowl = rt*16 + g4*4 + r;
                const ushort* gp = &gis[cur][0][r][768];
                float hp = b2f(hbf[cur][rowl][256]);
                float h2 = gruh(b2f(gp[0]) + bi0, b2f(gp[16]) + bi1, b2f(gp[32]) + bi2,
                                a0[r] + bh0, a1[r] + bh1, a2[r] + bh2, hp);
                hbf[cur^1][rowl][256] = f2b(h2);
                Cm[(size_t)(nb+r)*256 + ii*16 + j] = h2;
              }
            }
          } else if (g4 == 0) {
            #pragma unroll
            for (int r = 0; r < 4; ++r) {
              const ushort* gp = &gis[cur][1][r][768];
              float hp = b2f(hbf[cur][64 + r][256]);
              float h2 = gruh(b2f(gp[0]) + bi0, b2f(gp[16]) + bi1, b2f(gp[32]) + bi2,
                              a0[r] + bh0, a1[r] + bh1, a2[r] + bh2, hp);
              hbf[cur^1][64 + r][256] = f2b(h2);
              Bbf[((size_t)j*1024 + nb + r)*288 + 256] = f2b(h2);
            }
          }
        }
      }
    }
    BAR();
    cur ^= 1;
  }
}

// ---------- fused backward-K accumulate + Kmbf + C fill + wb dot ----------
__global__ void accum_wb(const ushort* __restrict__ Bbf, const float* __restrict__ Km,
                         ushort* __restrict__ Kmbf, float* __restrict__ Cm,
                         const float* __restrict__ ba, float* __restrict__ wbv){
  __shared__ float kms[16][257];
  int n = blockIdx.x, c = threadIdx.x;
  float s = 0.f;
  for (int jj = 15; jj >= 0; --jj) {
    if (jj < 15) s += b2f(Bbf[((size_t)(14-jj)*1024 + n)*288 + c]);
    size_t o = ((size_t)n*16 + jj)*256 + c;
    float v = Km[o] + s;
    Kmbf[o] = f2b(v);
    kms[jj][c] = v;
  }
  int i = c >> 4, j = c & 15;
  if (i > j) Cm[(size_t)n*256 + i*16 + j] = b2f(Bbf[((size_t)(i-1-j)*1024 + n)*288 + 256]);
  __syncthreads();
  int l = c >> 4, lane16 = c & 15;
  float t = 0.f;
  for (int m = lane16; m < 256; m += 16) t += kms[l][m]*ba[m];
  t += __shfl_down(t, 8, 16); t += __shfl_down(t, 4, 16);
  t += __shfl_down(t, 2, 16); t += __shfl_down(t, 1, 16);
  if (lane16 == 0) wbv[n*16 + l] = t;
}

// ---------- cell chunk (round-12 proven): 16 t-steps, Wh in VGPRs, Gi precomputed ----------
__global__ __launch_bounds__(512) __attribute__((amdgpu_waves_per_eu(2, 2))) void cell_chunk(
    const ushort* __restrict__ Gi, const ushort* __restrict__ Wh,
    const float* __restrict__ bhh, const float* __restrict__ hbuf,
    int t0, ushort* __restrict__ hcT, float* __restrict__ out){
  __shared__ __align__(16) ushort hbf[2][16][266];
  int tid = threadIdx.x, lane = tid & 63, wv = tid >> 6;
  int u = lane & 15, g4 = lane >> 4;
  int n0 = blockIdx.x * 16;
  int ktA = wv, ktB = wv + 8;
  int cA = ktA*16 + u, cB = ktB*16 + u;
  s16x8 WA0[8], WA1[8], WA2[8], WB0[8], WB1[8], WB2[8];
  #pragma unroll
  for (int q = 0; q < 8; ++q) {
    int off = q*32 + g4*8;
    WA0[q] = *(const s16x8*)(Wh + (size_t)((3*ktA+0)*16 + u)*256 + off);
    WA1[q] = *(const s16x8*)(Wh + (size_t)((3*ktA+1)*16 + u)*256 + off);
    WA2[q] = *(const s16x8*)(Wh + (size_t)((3*ktA+2)*16 + u)*256 + off);
    WB0[q] = *(const s16x8*)(Wh + (size_t)((3*ktB+0)*16 + u)*256 + off);
    WB1[q] = *(const s16x8*)(Wh + (size_t)((3*ktB+1)*16 + u)*256 + off);
    WB2[q] = *(const s16x8*)(Wh + (size_t)((3*ktB+2)*16 + u)*256 + off);
  }
  float bhgA = bhh[512 + cA], bhgB = bhh[512 + cB];
  if (t0 == 0) {
    for (int i = tid; i < 16*256; i += 512) {
      int rr = i >> 8, cc = i & 255;
      hbf[0][rr][cc] = f2b(hbuf[(size_t)(n0 + rr)*256 + cc]);
    }
  } else {
    for (int i = tid; i < 16*256; i += 512) {
      int rr = i >> 8, cc = i & 255;
      hbf[0][rr][cc] = hcT[((size_t)(t0-1)*1024 + n0 + rr)*256 + cc];
    }
  }
  BAR();
  int cur = 0;
  for (int s = 0; s < 16; ++s) {
    int t = t0 + s;
    f32x4 a0={0,0,0,0},a1={0,0,0,0},a2={0,0,0,0};
    f32x4 b0={0,0,0,0},b1={0,0,0,0},b2={0,0,0,0};
    #pragma unroll
    for (int q = 0; q < 8; ++q) {
      s16x8 ah = *(const s16x8*)&hbf[cur][u][q*32 + g4*8];
      a0 = MFMA16(ah, WA0[q], a0, 0,0,0);
      a1 = MFMA16(ah, WA1[q], a1, 0,0,0);
      a2 = MFMA16(ah, WA2[q], a2, 0,0,0);
      b0 = MFMA16(ah, WB0[q], b0, 0,0,0);
      b1 = MFMA16(ah, WB1[q], b1, 0,0,0);
      b2 = MFMA16(ah, WB2[q], b2, 0,0,0);
    }
    const ushort* gbase = Gi + (size_t)s*1024*768;
    #pragma unroll
    for (int r = 0; r < 4; ++r) {
      int row = g4*4 + r;
      const ushort* gr = gbase + (size_t)(n0 + row)*768;
      {
        float gir = b2f(gr[3*ktA*16 + u]);
        float giz = b2f(gr[3*ktA*16 + 16 + u]);
        float gig = b2f(gr[3*ktA*16 + 32 + u]);
        float hp  = b2f(hbf[cur][row][cA]);
        float rr2 = 1.f/(1.f + __expf(-(gir + a0[r])));
        float zz  = 1.f/(1.f + __expf(-(giz + a1[r])));
        float ex  = __expf(2.f*(gig + rr2*(a2[r] + bhgA)));
        float gg  = 1.f - 2.f/(ex + 1.f);
        float h2  = (1.f - zz)*gg + zz*hp;
        ushort hb = f2b(h2);
        hbf[cur^1][row][cA] = hb;
        hcT[((size_t)t*1024 + n0 + row)*256 + cA] = hb;
        out[((size_t)t*1024 + n0 + row)*STATE_ + 2 + cA] = h2;
        if (t == 63) out[((size_t)64*1024 + n0 + row)*STATE_ + 2 + cA] = h2;
      }
      {
        float gir = b2f(gr[3*ktB*16 + u]);
        float giz = b2f(gr[3*ktB*16 + 16 + u]);
        float gig = b2f(gr[3*ktB*16 + 32 + u]);
        float hp  = b2f(hbf[cur][row][cB]);
        float rr2 = 1.f/(1.f + __expf(-(gir + b0[r])));
        float zz  = 1.f/(1.f + __expf(-(giz + b1[r])));
        float ex  = __expf(2.f*(gig + rr2*(b2[r] + bhgB)));
        float gg  = 1.f - 2.f/(ex + 1.f);
        float h2  = (1.f - zz)*gg + zz*hp;
        ushort hb = f2b(h2);
        hbf[cur^1][row][cB] = hb;
        hcT[((size_t)t*1024 + n0 + row)*256 + cB] = hb;
        out[((size_t)t*1024 + n0 + row)*STATE_ + 2 + cB] = h2;
        if (t == 63) out[((size_t)64*1024 + n0 + row)*STATE_ + 2 + cB] = h2;
      }
    }
    BAR();
    cur ^= 1;
  }
}

// ---------- attention/softmax + a,v columns ----------
__global__ __launch_bounds__(256) void attn_v(
    const ushort* __restrict__ Ktl, const ushort* __restrict__ hcT,
    const float* __restrict__ wbv, const float* __restrict__ Cm,
    const float* __restrict__ p0, const int* __restrict__ act,
    const float* __restrict__ Wc, const float* __restrict__ bc,
    float* __restrict__ out){
  __shared__ float WcS[256];
  int n = blockIdx.x;
  int tid = threadIdx.x;
  WcS[tid] = Wc[tid];
  __syncthreads();
  int lane = tid & 63, wv = tid >> 6;
  int u = lane & 15, g4 = lane >> 4;
  int t0 = wv*16;
  const ushort* Ka = Ktl + ((size_t)n*16 + u)*256 + g4*8;
  const ushort* Hb = hcT + ((size_t)(t0 + u)*1024 + n)*256 + g4*8;
  f32x4 acc = {0,0,0,0};
  float vp = 0.f;
  #pragma unroll
  for (int q = 0; q < 8; ++q) {
    s16x8 av = *(const s16x8*)(Ka + q*32);
    s16x8 bv = *(const s16x8*)(Hb + q*32);
    acc = MFMA16(av, bv, acc, 0,0,0);
    #pragma unroll
    for (int j = 0; j < 8; ++j) vp += b2f((ushort)bv[j]) * WcS[q*32 + g4*8 + j];
  }
  vp += __shfl_xor(vp, 16, 64);
  vp += __shfl_xor(vp, 32, 64);
  float vfin = vp + bc[0];
  int t = t0 + u;
  float ps[4];
  if (t == 0) {
    #pragma unroll
    for (int r = 0; r < 4; ++r) {
      float catt = 0.f;
      for (int i = 0; i < 16; ++i) catt += p0[n*16 + i]*Cm[(size_t)n*256 + i*16 + g4*4 + r];
      ps[r] = (acc[r] + wbv[n*16 + g4*4 + r]) * catt;
    }
  } else {
    int ap = act[(size_t)(t-1)*1024 + n];
    #pragma unroll
    for (int r = 0; r < 4; ++r)
      ps[r] = (acc[r] + wbv[n*16 + g4*4 + r]) * Cm[(size_t)n*256 + ap*16 + g4*4 + r];
  }
  float mx = fmaxf(fmaxf(ps[0], ps[1]), fmaxf(ps[2], ps[3]));
  mx = fmaxf(mx, __shfl_xor(mx, 16, 64));
  mx = fmaxf(mx, __shfl_xor(mx, 32, 64));
  float e[4], se = 0.f;
  #pragma unroll
  for (int r = 0; r < 4; ++r) { e[r] = __expf(ps[r] - mx); se += e[r]; }
  se += __shfl_xor(se, 16, 64);
  se += __shfl_xor(se, 32, 64);
  float inv = 1.f/se;
  int a = act[(size_t)t*1024 + n];
  size_t ro = ((size_t)t*1024 + n)*STATE_;
  if (g4 == 0) { out[ro] = (float)a; out[ro + 1] = vfin; }
  #pragma unroll
  for (int r = 0; r < 4; ++r) {
    out[ro + 258 + g4*4 + r] = e[r]*inv;
    out[ro + 274 + g4*4 + r] = (g4*4 + r == a) ? 1.f : 0.f;
  }
  if (t == 63) {
    size_t r2 = ((size_t)64*1024 + n)*STATE_;
    if (g4 == 0) { out[r2] = (float)a; out[r2 + 1] = vfin; }
    #pragma unroll
    for (int r = 0; r < 4; ++r) {
      out[r2 + 258 + g4*4 + r] = e[r]*inv;
      out[r2 + 274 + g4*4 + r] = (g4*4 + r == a) ? 1.f : 0.f;
    }
  }
}

extern "C" void kernel_launch(void* const* d_in, const int* in_sizes, int n_in,
                              void* d_out, int out_size, void* d_ws, size_t ws_size,
                              hipStream_t stream){
  (void)in_sizes; (void)n_in; (void)out_size; (void)ws_size;
  const float* cond  = (const float*)d_in[0];
  const int*   lines = (const int*)  d_in[1];
  const int*   act   = (const int*)  d_in[2];
  const float* hxs   = (const float*)d_in[3];
  const float* emb   = (const float*)d_in[4];
  const float* wih_e = (const float*)d_in[5];
  const float* whh_e = (const float*)d_in[6];
  const float* bih_e = (const float*)d_in[7];
  const float* bhh_e = (const float*)d_in[8];
  const float* W1    = (const float*)d_in[9];
  const float* b1    = (const float*)d_in[10];
  const float* W2    = (const float*)d_in[11];
  const float* b2    = (const float*)d_in[12];
  const float* wih_c = (const float*)d_in[13];
  const float* whh_c = (const float*)d_in[14];
  const float* bih_c = (const float*)d_in[15];
  const float* bhh_c = (const float*)d_in[16];
  const float* Wa    = (const float*)d_in[17];
  const float* ba    = (const float*)d_in[18];
  const float* Wc    = (const float*)d_in[19];
  const float* bc    = (const float*)d_in[20];
  float* out = (float*)d_out;

  // ---- workspace layout (round-12 proven) ----
  char* base = (char*)d_ws;
  ushort* Mbf    = (ushort*)(base + 0);             // [16384,256]       P0-P3
  ushort* Bbf    = (ushort*)(base + 8388608);       // [16,1024,288]     P1-P2
  float*  Km     = (float*) (base + 17825792);      // [16384,256] f32   P1-P2
  ushort* Kmbf   = (ushort*)(base + 34603008);      // [16384,256]       P2
  ushort* xcat   = (ushort*)(base + 8388608);       // [65536,320]       P3 (over Bbf/Km/Kmbf)
  ushort* x2     = (ushort*)(base + 8388608);       // [65536,256]       P3 (over xcat)
  ushort* hcT    = (ushort*)(base + 8388608);       // [64,1024,256]     P4-P5 (over x2, per-t safe)
  ushort* GiAll  = (ushort*)(base + 50331648);      // [16384,832]       P1
  ushort* x1     = (ushort*)(base + 50331648);      // [65536,256]       P3
  ushort* GiC0   = (ushort*)(base + 50331648);      // [16,1024,768]     P4
  ushort* GiC1   = (ushort*)(base + 75497472);      // [16,1024,768]     P4
  ushort* Ktl    = (ushort*)(base + 100663296);     // [16384,256]       P2-P5
  float*  Cm     = (float*) (base + 109051904);     // [1024,16,16]
  float*  hbuf   = (float*) (base + 110100480);     // [1024,256]
  float*  p0     = (float*) (base + 111149056);     // [1024,16]
  float*  r0v    = (float*) (base + 111214592);     // [1024,256]
  float*  wbv    = (float*) (base + 112263168);     // [1024,16]
  ushort* wihe_p = (ushort*)(base + 112328704);     // [832,256]
  ushort* whhe_p = (ushort*)(base + 112754688);     // [832,288]
  ushort* wihc_p = (ushort*)(base + 113233920);     // [768,256]
  ushort* whhc_p = (ushort*)(base + 113627136);     // [768,256]
  ushort* W1b    = (ushort*)(base + 114020352);     // [256,320]
  ushort* W2b    = (ushort*)(base + 114184192);     // [256,256]
  ushort* WaTb   = (ushort*)(base + 114315264);     // [256,256]
  float*  cbias  = (float*) (base + 114446336);     // [768]

  prep_all<<<4139, 256, 0, stream>>>(wih_e, whh_e, wihe_p, whhe_p,
                                     wih_c, whh_c, wihc_p, whhc_p,
                                     bih_c, bhh_c, cbias, W1, W1b, W2, W2b, Wa, WaTb);
  emb_init_r0<<<1024, 256, 0, stream>>>(lines, emb, hxs, Mbf, hbuf, p0, r0v);

  gemm_mfma<0><<<dim3(256, 13), 256, 0, stream>>>(Mbf, wihe_p, nullptr, GiAll, 256, 832);
  enc_all<<<256, 512, 0, stream>>>(GiAll, whhe_p, bih_e, bhh_e, Km, Cm, Bbf);
  accum_wb<<<1024, 256, 0, stream>>>(Bbf, Km, Kmbf, Cm, ba, wbv);
  gemm_mfma<0><<<dim3(256, 4), 256, 0, stream>>>(Kmbf, WaTb, nullptr, Ktl, 256, 256);

  build_xcat8<<<10240, 256, 0, stream>>>(cond, act, r0v, Mbf, xcat);
  gemm_mfma<1><<<dim3(1024, 4), 256, 0, stream>>>(xcat, W1b, b1, x1, 320, 256);
  gemm_mfma<1><<<dim3(1024, 4), 256, 0, stream>>>(x1, W2b, b2, x2, 256, 256);

  // cell phase: gi precompute chunks (ping-pong) + weight-stationary cell chunks
  ushort* gic[2] = {GiC0, GiC1};
  gemm_mfma<0><<<dim3(256, 12), 256, 0, stream>>>(x2 + (size_t)0*16384*256, wihc_p, cbias, gic[0], 256, 768);
  gemm_mfma<0><<<dim3(256, 12), 256, 0, stream>>>(x2 + (size_t)1*16384*256, wihc_p, cbias, gic[1], 256, 768);
  cell_chunk<<<64, 512, 0, stream>>>(gic[0], whhc_p, bhh_c, hbuf,  0, hcT, out);
  gemm_mfma<0><<<dim3(256, 12), 256, 0, stream>>>(x2 + (size_t)2*16384*256, wihc_p, cbias, gic[0], 256, 768);
  cell_chunk<<<64, 512, 0, stream>>>(gic[1], whhc_p, bhh_c, hbuf, 16, hcT, out);
  gemm_mfma<0><<<dim3(256, 12), 256, 0, stream>>>(x2 + (size_t)3*16384*256, wihc_p, cbias, gic[1], 256, 768);
  cell_chunk<<<64, 512, 0, stream>>>(gic[0], whhc_p, bhh_c, hbuf, 32, hcT, out);
  cell_chunk<<<64, 512, 0, stream>>>(gic[1], whhc_p, bhh_c, hbuf, 48, hcT, out);

  attn_v<<<1024, 256, 0, stream>>>(Ktl, hcT, wbv, Cm, p0, act, Wc, bc, out);
}

// Round 15
// 884.411 us; speedup vs baseline: 1.9584x; 1.3397x over previous
//
#include <hip/hip_runtime.h>
#include <hip/hip_bf16.h>
#include <cstddef>

#define T_ 64
#define N_ 1024
#define L_ 16
#define H_ 256
#define STATE_ 290
#define EKSTR 296   // enc hbf row stride (ushorts): 592B = 37*16, b128-aligned

typedef short s16x8 __attribute__((ext_vector_type(8)));
typedef float f32x4 __attribute__((ext_vector_type(4)));
typedef ushort us4 __attribute__((ext_vector_type(4)));
typedef ushort us8 __attribute__((ext_vector_type(8)));
#define MFMA16 __builtin_amdgcn_mfma_f32_16x16x32_bf16

// raw barrier: wait LDS ops only, do NOT drain global stores.
#define BAR() asm volatile("s_waitcnt lgkmcnt(0)\n\ts_barrier" ::: "memory")

__device__ __forceinline__ float b2f(ushort u){ return __uint_as_float(((unsigned)u) << 16); }
__device__ __forceinline__ ushort f2b(float f){
  unsigned x = __float_as_uint(f);
  return (ushort)((x + 0x7FFFu + ((x >> 16) & 1u)) >> 16);
}
__device__ __forceinline__ float gruh(float gir,float giz,float gig,
                                      float ghr,float ghz,float ghg,float hp){
  float r = 1.f/(1.f + __expf(-(gir + ghr)));
  float z = 1.f/(1.f + __expf(-(giz + ghz)));
  float g = tanhf(gig + r*ghg);
  return (1.f - z)*g + z*hp;
}

// ---------- fused weight prep: all permutes/converts in ONE launch ----------
__global__ void prep_all(
    const float* __restrict__ wih_e, const float* __restrict__ whh_e,
    ushort* __restrict__ wihe_p, ushort* __restrict__ whhe_p,
    const float* __restrict__ wih_c, const float* __restrict__ whh_c,
    ushort* __restrict__ wihc_p, ushort* __restrict__ whhc_p,
    const float* __restrict__ bih_c, const float* __restrict__ bhh_c, float* __restrict__ cb,
    const float* __restrict__ W1, ushort* __restrict__ W1b,
    const float* __restrict__ W2, ushort* __restrict__ W2b,
    const float* __restrict__ Wa, ushort* __restrict__ WaTb){
  int b = blockIdx.x, t = threadIdx.x;
  if (b < 832) {                       // perm wih_e [771,256] -> [832,256]
    int idx = b*256 + t;
    int d = idx >> 8, c = idx & 255;
    int tile = d >> 4, uu = d & 15;
    int k = tile/3, p = tile - 3*k;
    int hc = k*16 + uu;
    bool ok = (tile < 51) && (hc < 257);
    wihe_p[idx] = ok ? f2b(wih_e[(size_t)(p*257 + hc)*256 + c]) : (ushort)0;
  } else if (b < 1768) {               // perm whh_e [771,257] -> [832,288]
    int idx = (b-832)*256 + t;
    int d = idx / 288, c = idx - d*288;
    int tile = d >> 4, uu = d & 15;
    int k = tile/3, p = tile - 3*k;
    int hc = k*16 + uu;
    bool ok = (tile < 51) && (hc < 257) && (c < 257);
    whhe_p[idx] = ok ? f2b(whh_e[(size_t)(p*257 + hc)*257 + c]) : (ushort)0;
  } else if (b < 2536) {               // perm wih_c [768,256]
    int idx = (b-1768)*256 + t;
    int d = idx >> 8, c = idx & 255;
    int tile = d >> 4, uu = d & 15;
    int k = tile/3, p = tile - 3*k;
    wihc_p[idx] = f2b(wih_c[(size_t)(p*256 + k*16 + uu)*256 + c]);
  } else if (b < 3304) {               // perm whh_c [768,256]
    int idx = (b-2536)*256 + t;
    int d = idx >> 8, c = idx & 255;
    int tile = d >> 4, uu = d & 15;
    int k = tile/3, p = tile - 3*k;
    whhc_p[idx] = f2b(whh_c[(size_t)(p*256 + k*16 + uu)*256 + c]);
  } else if (b < 3307) {               // cbias (r,z: bih+bhh; g: bih)
    int d = (b-3304)*256 + t;
    if (d < 768) {
      int tile = d >> 4, uu = d & 15;
      int k = tile/3, p = tile - 3*k;
      int src = p*256 + k*16 + uu;
      cb[d] = bih_c[src] + (p < 2 ? bhh_c[src] : 0.f);
    }
  } else if (b < 3627) {               // W1 convert [256,320]
    int idx = (b-3307)*256 + t;
    W1b[idx] = f2b(W1[idx]);
  } else if (b < 3883) {               // W2 convert [256,256]
    int idx = (b-3627)*256 + t;
    W2b[idx] = f2b(W2[idx]);
  } else {                             // Wa transpose -> bf16
    int m = b - 3883;
    WaTb[(size_t)t*256 + m] = f2b(Wa[(size_t)m*256 + t]);
  }
}

// ---------- fused embed + init_state + r0 ----------
__global__ void emb_init_r0(
    const int* __restrict__ lines, const float* __restrict__ emb, const float* __restrict__ hxs,
    ushort* __restrict__ Mbf, float* __restrict__ hbuf, float* __restrict__ p0,
    float* __restrict__ r0v){
  __shared__ ushort Ms[16][256];
  __shared__ float p0s[16];
  __shared__ int ls[16];
  __shared__ int nz;
  int n = blockIdx.x, t = threadIdx.x;
  if (t == 0) nz = 0;
  if (t < 16) ls[t] = lines[n*16 + t];
  __syncthreads();
  #pragma unroll
  for (int l = 0; l < 16; ++l) {
    ushort v = f2b(emb[(size_t)ls[l]*256 + t]);
    Ms[l][t] = v;
    Mbf[((size_t)n*16 + l)*256 + t] = v;
  }
  for (int c = t; c < STATE_; c += 256)
    if (hxs[(size_t)n*STATE_ + c] != 0.f) atomicOr(&nz, 1);
  __syncthreads();
  bool new_ep = (nz == 0);
  hbuf[(size_t)n*256 + t] = hxs[(size_t)n*STATE_ + 2 + t];
  if (t < 16) {
    float pv = hxs[(size_t)n*STATE_ + 2 + 256 + 16 + t];
    if (t == 0 && new_ep) pv = 1.f;
    p0[n*16 + t] = pv;
    p0s[t] = pv;
  }
  __syncthreads();
  float s = 0.f;
  #pragma unroll
  for (int l = 0; l < 16; ++l) s += p0s[l]*b2f(Ms[l][t]);
  r0v[(size_t)n*256 + t] = s;
}

__global__ void build_xcat8(const float* __restrict__ cond, const int* __restrict__ act,
                            const float* __restrict__ r0v, const ushort* __restrict__ Mbf,
                            ushort* __restrict__ xcat){
  int idx = blockIdx.x*256 + threadIdx.x;
  if (idx >= T_*N_*40) return;
  int kc = idx % 40;
  int row = idx / 40;
  int n = row & 1023, t = row >> 10;
  us8 v;
  if (kc < 8) {
    const float* cp = cond + (size_t)row*64 + kc*8;
    #pragma unroll
    for (int i = 0; i < 8; ++i) v[i] = f2b(cp[i]);
  } else if (t == 0) {
    const float* rp = r0v + (size_t)n*256 + (kc-8)*8;
    #pragma unroll
    for (int i = 0; i < 8; ++i) v[i] = f2b(rp[i]);
  } else {
    int a = act[(size_t)(t-1)*1024 + n];
    v = *(const us8*)(Mbf + ((size_t)n*16 + a)*256 + (kc-8)*8);
  }
  *(us8*)(xcat + (size_t)idx*8) = v;
}

// ---------- MFMA GEMM with LDS-staged W tile (kills 4x duplicate L2 B-reads) ----------
// out[r,col] = act(sum_k A[r,k]*W[col,k] + bias[col]), bf16 out. ldw = Kd+8 pad -> <=2-way banks.
template<int RELU>
__global__ __launch_bounds__(256) void gemm_mfma(
    const ushort* __restrict__ A, const ushort* __restrict__ W,
    const float* __restrict__ bias, ushort* __restrict__ out,
    int Kd, int ldo){
  __shared__ __align__(16) ushort Ws[64*328];
  int lane = threadIdx.x & 63, wv = threadIdx.x >> 6;
  int u = lane & 15, g4 = lane >> 4;
  int br = blockIdx.x*64 + wv*16;
  int bm = blockIdx.y*64;
  int ldw = Kd + 8;
  for (int i = threadIdx.x; i < 8*Kd; i += 256) {   // 64*Kd elems in us8 chunks
    int e = i*8;
    int row = e / Kd, col = e - row*Kd;
    *(us8*)&Ws[row*ldw + col] = *(const us8*)(W + (size_t)(bm + row)*Kd + col);
  }
  __syncthreads();
  const ushort* Arow = A + (size_t)(br + u)*Kd + g4*8;
  f32x4 acc0 = {0,0,0,0}, acc1 = {0,0,0,0}, acc2 = {0,0,0,0}, acc3 = {0,0,0,0};
  for (int k0 = 0; k0 < Kd; k0 += 32) {
    s16x8 av = *(const s16x8*)(Arow + k0);
    s16x8 b0 = *(const s16x8*)&Ws[( 0 + u)*ldw + k0 + g4*8];
    s16x8 b1 = *(const s16x8*)&Ws[(16 + u)*ldw + k0 + g4*8];
    s16x8 b2 = *(const s16x8*)&Ws[(32 + u)*ldw + k0 + g4*8];
    s16x8 b3 = *(const s16x8*)&Ws[(48 + u)*ldw + k0 + g4*8];
    acc0 = MFMA16(av, b0, acc0, 0,0,0);
    acc1 = MFMA16(av, b1, acc1, 0,0,0);
    acc2 = MFMA16(av, b2, acc2, 0,0,0);
    acc3 = MFMA16(av, b3, acc3, 0,0,0);
  }
  f32x4 ac[4] = {acc0, acc1, acc2, acc3};
  #pragma unroll
  for (int mt = 0; mt < 4; ++mt) {
    int col = bm + mt*16 + u;
    float b = bias ? bias[col] : 0.f;
    #pragma unroll
    for (int r = 0; r < 4; ++r) {
      float v = ac[mt][r] + b;
      if (RELU) v = fmaxf(v, 0.f);
      out[(size_t)(br + g4*4 + r)*ldo + col] = f2b(v);
    }
  }
}

// ---------- unified encoder (round-12 proven: ~319us, spill-free, VGPR 100) ----------
__global__ __launch_bounds__(512) __attribute__((amdgpu_waves_per_eu(2, 2))) void enc_all(
    const ushort* __restrict__ GiAll, const ushort* __restrict__ Wh,
    const float* __restrict__ bih, const float* __restrict__ bhh,
    float* __restrict__ Km, float* __restrict__ Cm, ushort* __restrict__ Bbf){
  __shared__ __align__(16) ushort hbf[2][80][EKSTR];
  __shared__ __align__(16) ushort gis[2][2][4][832];
  int tid = threadIdx.x, lane = tid & 63, wv = tid >> 6;
  int u = lane & 15, g4 = lane >> 4;
  int nb = blockIdx.x * 4;
  for (int i = tid; i < 2*80*EKSTR; i += 512) ((ushort*)hbf)[i] = 0;
  #pragma unroll
  for (int i0 = 0; i0 < 4; ++i0) {
    int i = tid + i0*512;
    if (i < 1664) {
      int flat = i*4;
      int fb = flat / 3328, rem = flat - fb*3328;
      int nl = rem / 832, k = rem - nl*832;
      int row = (nb+nl)*16 + (fb ? 15 : 0);
      *(us4*)&gis[0][fb][nl][k] = *(const us4*)(GiAll + (size_t)row*832 + k);
    }
  }
  BAR();
  int cur = 0;
  for (int j = 0; j < 16; ++j) {
    if (j < 15) {
      #pragma unroll
      for (int i0 = 0; i0 < 4; ++i0) {
        int i = tid + i0*512;
        if (i < 1664) {
          int flat = i*4;
          int fb = flat / 3328, rem = flat - fb*3328;
          int nl = rem / 832, k = rem - nl*832;
          int row = (nb+nl)*16 + (fb ? (14-j) : (j+1));
          *(us4*)&gis[cur^1][fb][nl][k] = *(const us4*)(GiAll + (size_t)row*832 + k);
        }
      }
    }
    #pragma unroll 1
    for (int tt = 0; tt < 2; ++tt) {
      int kt = 2*wv + tt;
      f32x4 acc[5][3];
      #pragma unroll
      for (int rt = 0; rt < 5; ++rt) {
        acc[rt][0] = (f32x4){0,0,0,0};
        acc[rt][1] = (f32x4){0,0,0,0};
        acc[rt][2] = (f32x4){0,0,0,0};
      }
      #pragma unroll
      for (int q = 0; q < 9; ++q) {
        int off = q*32 + g4*8;
        s16x8 w0 = *(const s16x8*)(Wh + (size_t)((3*kt+0)*16 + u)*288 + off);
        s16x8 w1 = *(const s16x8*)(Wh + (size_t)((3*kt+1)*16 + u)*288 + off);
        s16x8 w2 = *(const s16x8*)(Wh + (size_t)((3*kt+2)*16 + u)*288 + off);
        #pragma unroll
        for (int rt = 0; rt < 5; ++rt) {
          if (rt < 4 && rt*4 > j) continue;
          s16x8 av = *(const s16x8*)&hbf[cur][rt*16 + u][off];
          acc[rt][0] = MFMA16(av, w0, acc[rt][0], 0,0,0);
          acc[rt][1] = MFMA16(av, w1, acc[rt][1], 0,0,0);
          acc[rt][2] = MFMA16(av, w2, acc[rt][2], 0,0,0);
        }
      }
      int c = kt*16 + u;
      float bi0 = bih[c], bi1 = bih[257+c], bi2 = bih[514+c];
      float bh0 = bhh[c], bh1 = bhh[257+c], bh2 = bhh[514+c];
      float kmP[4] = {0.f, 0.f, 0.f, 0.f};
      #pragma unroll
      for (int rt = 0; rt < 4; ++rt) {
        int ii = rt*4 + g4;
        if (rt*4 <= j && ii <= j) {
          #pragma unroll
          for (int r = 0; r < 4; ++r) {
            int rowl = rt*16 + g4*4 + r;
            const ushort* gp = &gis[cur][0][r][3*kt*16];
            float hp = b2f(hbf[cur][rowl][c]);
            float h2 = gruh(b2f(gp[u]) + bi0, b2f(gp[16+u]) + bi1, b2f(gp[32+u]) + bi2,
                            acc[rt][0][r] + bh0, acc[rt][1][r] + bh1,
                            acc[rt][2][r] + bh2, hp);
            hbf[cur^1][rowl][c] = f2b(h2);
            kmP[r] += h2;
          }
        }
      }
      #pragma unroll
      for (int r = 0; r < 4; ++r) {
        float s = kmP[r];
        s += __shfl_xor(s, 16, 64);
        s += __shfl_xor(s, 32, 64);
        if (g4 == 0) Km[((size_t)(nb+r)*16 + j)*256 + c] = s;
      }
      if (g4 == 0) {
        #pragma unroll
        for (int r = 0; r < 4; ++r) {
          const ushort* gp = &gis[cur][1][r][3*kt*16];
          float hp = b2f(hbf[cur][64 + r][c]);
          float h2 = gruh(b2f(gp[u]) + bi0, b2f(gp[16+u]) + bi1, b2f(gp[32+u]) + bi2,
                          acc[4][0][r] + bh0, acc[4][1][r] + bh1,
                          acc[4][2][r] + bh2, hp);
          hbf[cur^1][64 + r][c] = f2b(h2);
          Bbf[((size_t)j*1024 + nb + r)*288 + c] = f2b(h2);
        }
      }
    }
    if (wv < 5) {
      int rt = wv;
      bool go = (rt == 4) || (rt*4 <= j);
      if (go) {
        f32x4 a0 = {0,0,0,0}, a1 = {0,0,0,0}, a2 = {0,0,0,0};
        #pragma unroll
        for (int q = 0; q < 9; ++q) {
          int off = q*32 + g4*8;
          s16x8 w0 = *(const s16x8*)(Wh + (size_t)(48*16 + u)*288 + off);
          s16x8 w1 = *(const s16x8*)(Wh + (size_t)(49*16 + u)*288 + off);
          s16x8 w2 = *(const s16x8*)(Wh + (size_t)(50*16 + u)*288 + off);
          s16x8 av = *(const s16x8*)&hbf[cur][rt*16 + u][off];
          a0 = MFMA16(av, w0, a0, 0,0,0);
          a1 = MFMA16(av, w1, a1, 0,0,0);
          a2 = MFMA16(av, w2, a2, 0,0,0);
        }
        if (u == 0) {
          float bi0 = bih[256], bi1 = bih[513], bi2 = bih[770];
          float bh0 = bhh[256], bh1 = bhh[513], bh2 = bhh[770];
          if (rt < 4) {
            int ii = rt*4 + g4;
            if (ii <= j) {
              #pragma unroll
              for (int r = 0; r < 4; ++r) {
                int rowl = rt*16 + g4*4 + r;
                const ushort* gp = &gis[cur][0][r][768];
                float hp = b2f(hbf[cur][rowl][256]);
                float h2 = gruh(b2f(gp[0]) + bi0, b2f(gp[16]) + bi1, b2f(gp[32]) + bi2,
                                a0[r] + bh0, a1[r] + bh1, a2[r] + bh2, hp);
                hbf[cur^1][rowl][256] = f2b(h2);
                Cm[(size_t)(nb+r)*256 + ii*16 + j] = h2;
              }
            }
          } else if (g4 == 0) {
            #pragma unroll
            for (int r = 0; r < 4; ++r) {
              const ushort* gp = &gis[cur][1][r][768];
              float hp = b2f(hbf[cur][64 + r][256]);
              float h2 = gruh(b2f(gp[0]) + bi0, b2f(gp[16]) + bi1, b2f(gp[32]) + bi2,
                              a0[r] + bh0, a1[r] + bh1, a2[r] + bh2, hp);
              hbf[cur^1][64 + r][256] = f2b(h2);
              Bbf[((size_t)j*1024 + nb + r)*288 + 256] = f2b(h2);
            }
          }
        }
      }
    }
    BAR();
    cur ^= 1;
  }
}

// ---------- fused backward-K accumulate + Kmbf + C fill + wb dot ----------
__global__ void accum_wb(const ushort* __restrict__ Bbf, const float* __restrict__ Km,
                         ushort* __restrict__ Kmbf, float* __restrict__ Cm,
                         const float* __restrict__ ba, float* __restrict__ wbv){
  __shared__ float kms[16][257];
  int n = blockIdx.x, c = threadIdx.x;
  float s = 0.f;
  for (int jj = 15; jj >= 0; --jj) {
    if (jj < 15) s += b2f(Bbf[((size_t)(14-jj)*1024 + n)*288 + c]);
    size_t o = ((size_t)n*16 + jj)*256 + c;
    float v = Km[o] + s;
    Kmbf[o] = f2b(v);
    kms[jj][c] = v;
  }
  int i = c >> 4, j = c & 15;
  if (i > j) Cm[(size_t)n*256 + i*16 + j] = b2f(Bbf[((size_t)(i-1-j)*1024 + n)*288 + 256]);
  __syncthreads();
  int l = c >> 4, lane16 = c & 15;
  float t = 0.f;
  for (int m = lane16; m < 256; m += 16) t += kms[l][m]*ba[m];
  t += __shfl_down(t, 8, 16); t += __shfl_down(t, 4, 16);
  t += __shfl_down(t, 2, 16); t += __shfl_down(t, 1, 16);
  if (lane16 == 0) wbv[n*16 + l] = t;
}

// ---------- cell chunk: 16 t-steps, Wh in VGPRs, Gi LDS-staged (dbuf prefetch) ----------
__global__ __launch_bounds__(512) __attribute__((amdgpu_waves_per_eu(2, 2))) void cell_chunk(
    const ushort* __restrict__ Gi, const ushort* __restrict__ Wh,
    const float* __restrict__ bhh, const float* __restrict__ hbuf,
    int t0, ushort* __restrict__ hcT, float* __restrict__ out){
  __shared__ __align__(16) ushort hbf[2][16][266];
  __shared__ __align__(16) ushort gis[2][16][768];   // 48KB: per-step gate slice
  int tid = threadIdx.x, lane = tid & 63, wv = tid >> 6;
  int u = lane & 15, g4 = lane >> 4;
  int n0 = blockIdx.x * 16;
  int ktA = wv, ktB = wv + 8;
  int cA = ktA*16 + u, cB = ktB*16 + u;
  s16x8 WA0[8], WA1[8], WA2[8], WB0[8], WB1[8], WB2[8];
  #pragma unroll
  for (int q = 0; q < 8; ++q) {
    int off = q*32 + g4*8;
    WA0[q] = *(const s16x8*)(Wh + (size_t)((3*ktA+0)*16 + u)*256 + off);
    WA1[q] = *(const s16x8*)(Wh + (size_t)((3*ktA+1)*16 + u)*256 + off);
    WA2[q] = *(const s16x8*)(Wh + (size_t)((3*ktA+2)*16 + u)*256 + off);
    WB0[q] = *(const s16x8*)(Wh + (size_t)((3*ktB+0)*16 + u)*256 + off);
    WB1[q] = *(const s16x8*)(Wh + (size_t)((3*ktB+1)*16 + u)*256 + off);
    WB2[q] = *(const s16x8*)(Wh + (size_t)((3*ktB+2)*16 + u)*256 + off);
  }
  float bhgA = bhh[512 + cA], bhgB = bhh[512 + cB];
  if (t0 == 0) {
    for (int i = tid; i < 16*256; i += 512) {
      int rr = i >> 8, cc = i & 255;
      hbf[0][rr][cc] = f2b(hbuf[(size_t)(n0 + rr)*256 + cc]);
    }
  } else {
    for (int i = tid; i < 16*256; i += 512) {
      int rr = i >> 8, cc = i & 255;
      hbf[0][rr][cc] = hcT[((size_t)(t0-1)*1024 + n0 + rr)*256 + cc];
    }
  }
  // initial gi slice (s=0): 16 rows x 768, linear us8 copy
  for (int i = tid; i < 1536; i += 512)
    *(us8*)&((ushort*)gis[0])[i*8] = *(const us8*)(Gi + (size_t)n0*768 + i*8);
  BAR();
  int cur = 0;
  for (int s = 0; s < 16; ++s) {
    int t = t0 + s;
    // prefetch next step's gi slice into the other buffer (hidden under MFMA)
    if (s < 15) {
      const ushort* src = Gi + (size_t)(s+1)*1024*768 + (size_t)n0*768;
      for (int i = tid; i < 1536; i += 512)
        *(us8*)&((ushort*)gis[cur^1])[i*8] = *(const us8*)(src + i*8);
    }
    f32x4 a0={0,0,0,0},a1={0,0,0,0},a2={0,0,0,0};
    f32x4 b0={0,0,0,0},b1={0,0,0,0},b2={0,0,0,0};
    #pragma unroll
    for (int q = 0; q < 8; ++q) {
      s16x8 ah = *(const s16x8*)&hbf[cur][u][q*32 + g4*8];
      a0 = MFMA16(ah, WA0[q], a0, 0,0,0);
      a1 = MFMA16(ah, WA1[q], a1, 0,0,0);
      a2 = MFMA16(ah, WA2[q], a2, 0,0,0);
      b0 = MFMA16(ah, WB0[q], b0, 0,0,0);
      b1 = MFMA16(ah, WB1[q], b1, 0,0,0);
      b2 = MFMA16(ah, WB2[q], b2, 0,0,0);
    }
    #pragma unroll
    for (int r = 0; r < 4; ++r) {
      int row = g4*4 + r;
      const ushort* gr = &gis[cur][row][0];
      {
        float gir = b2f(gr[3*ktA*16 + u]);
        float giz = b2f(gr[3*ktA*16 + 16 + u]);
        float gig = b2f(gr[3*ktA*16 + 32 + u]);
        float hp  = b2f(hbf[cur][row][cA]);
        float rr2 = 1.f/(1.f + __expf(-(gir + a0[r])));
        float zz  = 1.f/(1.f + __expf(-(giz + a1[r])));
        float ex  = __expf(2.f*(gig + rr2*(a2[r] + bhgA)));
        float gg  = 1.f - 2.f/(ex + 1.f);
        float h2  = (1.f - zz)*gg + zz*hp;
        ushort hb = f2b(h2);
        hbf[cur^1][row][cA] = hb;
        hcT[((size_t)t*1024 + n0 + row)*256 + cA] = hb;
        out[((size_t)t*1024 + n0 + row)*STATE_ + 2 + cA] = h2;
        if (t == 63) out[((size_t)64*1024 + n0 + row)*STATE_ + 2 + cA] = h2;
      }
      {
        float gir = b2f(gr[3*ktB*16 + u]);
        float giz = b2f(gr[3*ktB*16 + 16 + u]);
        float gig = b2f(gr[3*ktB*16 + 32 + u]);
        float hp  = b2f(hbf[cur][row][cB]);
        float rr2 = 1.f/(1.f + __expf(-(gir + b0[r])));
        float zz  = 1.f/(1.f + __expf(-(giz + b1[r])));
        float ex  = __expf(2.f*(gig + rr2*(b2[r] + bhgB)));
        float gg  = 1.f - 2.f/(ex + 1.f);
        float h2  = (1.f - zz)*gg + zz*hp;
        ushort hb = f2b(h2);
        hbf[cur^1][row][cB] = hb;
        hcT[((size_t)t*1024 + n0 + row)*256 + cB] = hb;
        out[((size_t)t*1024 + n0 + row)*STATE_ + 2 + cB] = h2;
        if (t == 63) out[((size_t)64*1024 + n0 + row)*STATE_ + 2 + cB] = h2;
      }
    }
    BAR();
    cur ^= 1;
  }
}

// ---------- attention/softmax + a,v columns ----------
__global__ __launch_bounds__(256) void attn_v(
    const ushort* __restrict__ Ktl, const ushort* __restrict__ hcT,
    const float* __restrict__ wbv, const float* __restrict__ Cm,
    const float* __restrict__ p0, const int* __restrict__ act,
    const float* __restrict__ Wc, const float* __restrict__ bc,
    float* __restrict__ out){
  __shared__ float WcS[256];
  int n = blockIdx.x;
  int tid = threadIdx.x;
  WcS[tid] = Wc[tid];
  __syncthreads();
  int lane = tid & 63, wv = tid >> 6;
  int u = lane & 15, g4 = lane >> 4;
  int t0 = wv*16;
  const ushort* Ka = Ktl + ((size_t)n*16 + u)*256 + g4*8;
  const ushort* Hb = hcT + ((size_t)(t0 + u)*1024 + n)*256 + g4*8;
  f32x4 acc = {0,0,0,0};
  float vp = 0.f;
  #pragma unroll
  for (int q = 0; q < 8; ++q) {
    s16x8 av = *(const s16x8*)(Ka + q*32);
    s16x8 bv = *(const s16x8*)(Hb + q*32);
    acc = MFMA16(av, bv, acc, 0,0,0);
    #pragma unroll
    for (int j = 0; j < 8; ++j) vp += b2f((ushort)bv[j]) * WcS[q*32 + g4*8 + j];
  }
  vp += __shfl_xor(vp, 16, 64);
  vp += __shfl_xor(vp, 32, 64);
  float vfin = vp + bc[0];
  int t = t0 + u;
  float ps[4];
  if (t == 0) {
    #pragma unroll
    for (int r = 0; r < 4; ++r) {
      float catt = 0.f;
      for (int i = 0; i < 16; ++i) catt += p0[n*16 + i]*Cm[(size_t)n*256 + i*16 + g4*4 + r];
      ps[r] = (acc[r] + wbv[n*16 + g4*4 + r]) * catt;
    }
  } else {
    int ap = act[(size_t)(t-1)*1024 + n];
    #pragma unroll
    for (int r = 0; r < 4; ++r)
      ps[r] = (acc[r] + wbv[n*16 + g4*4 + r]) * Cm[(size_t)n*256 + ap*16 + g4*4 + r];
  }
  float mx = fmaxf(fmaxf(ps[0], ps[1]), fmaxf(ps[2], ps[3]));
  mx = fmaxf(mx, __shfl_xor(mx, 16, 64));
  mx = fmaxf(mx, __shfl_xor(mx, 32, 64));
  float e[4], se = 0.f;
  #pragma unroll
  for (int r = 0; r < 4; ++r) { e[r] = __expf(ps[r] - mx); se += e[r]; }
  se += __shfl_xor(se, 16, 64);
  se += __shfl_xor(se, 32, 64);
  float inv = 1.f/se;
  int a = act[(size_t)t*1024 + n];
  size_t ro = ((size_t)t*1024 + n)*STATE_;
  if (g4 == 0) { out[ro] = (float)a; out[ro + 1] = vfin; }
  #pragma unroll
  for (int r = 0; r < 4; ++r) {
    out[ro + 258 + g4*4 + r] = e[r]*inv;
    out[ro + 274 + g4*4 + r] = (g4*4 + r == a) ? 1.f : 0.f;
  }
  if (t == 63) {
    size_t r2 = ((size_t)64*1024 + n)*STATE_;
    if (g4 == 0) { out[r2] = (float)a; out[r2 + 1] = vfin; }
    #pragma unroll
    for (int r = 0; r < 4; ++r) {
      out[r2 + 258 + g4*4 + r] = e[r]*inv;
      out[r2 + 274 + g4*4 + r] = (g4*4 + r == a) ? 1.f : 0.f;
    }
  }
}

extern "C" void kernel_launch(void* const* d_in, const int* in_sizes, int n_in,
                              void* d_out, int out_size, void* d_ws, size_t ws_size,
                              hipStream_t stream){
  (void)in_sizes; (void)n_in; (void)out_size; (void)ws_size;
  const float* cond  = (const float*)d_in[0];
  const int*   lines = (const int*)  d_in[1];
  const int*   act   = (const int*)  d_in[2];
  const float* hxs   = (const float*)d_in[3];
  const float* emb   = (const float*)d_in[4];
  const float* wih_e = (const float*)d_in[5];
  const float* whh_e = (const float*)d_in[6];
  const float* bih_e = (const float*)d_in[7];
  const float* bhh_e = (const float*)d_in[8];
  const float* W1    = (const float*)d_in[9];
  const float* b1    = (const float*)d_in[10];
  const float* W2    = (const float*)d_in[11];
  const float* b2    = (const float*)d_in[12];
  const float* wih_c = (const float*)d_in[13];
  const float* whh_c = (const float*)d_in[14];
  const float* bih_c = (const float*)d_in[15];
  const float* bhh_c = (const float*)d_in[16];
  const float* Wa    = (const float*)d_in[17];
  const float* ba    = (const float*)d_in[18];
  const float* Wc    = (const float*)d_in[19];
  const float* bc    = (const float*)d_in[20];
  float* out = (float*)d_out;

  // ---- workspace layout (round-12 proven) ----
  char* base = (char*)d_ws;
  ushort* Mbf    = (ushort*)(base + 0);             // [16384,256]       P0-P3
  ushort* Bbf    = (ushort*)(base + 8388608);       // [16,1024,288]     P1-P2
  float*  Km     = (float*) (base + 17825792);      // [16384,256] f32   P1-P2
  ushort* Kmbf   = (ushort*)(base + 34603008);      // [16384,256]       P2
  ushort* xcat   = (ushort*)(base + 8388608);       // [65536,320]       P3 (over Bbf/Km/Kmbf)
  ushort* x2     = (ushort*)(base + 8388608);       // [65536,256]       P3 (over xcat)
  ushort* hcT    = (ushort*)(base + 8388608);       // [64,1024,256]     P4-P5 (over x2, per-t safe)
  ushort* GiAll  = (ushort*)(base + 50331648);      // [16384,832]       P1
  ushort* x1     = (ushort*)(base + 50331648);      // [65536,256]       P3
  ushort* GiC0   = (ushort*)(base + 50331648);      // [16,1024,768]     P4
  ushort* GiC1   = (ushort*)(base + 75497472);      // [16,1024,768]     P4
  ushort* Ktl    = (ushort*)(base + 100663296);     // [16384,256]       P2-P5
  float*  Cm     = (float*) (base + 109051904);     // [1024,16,16]
  float*  hbuf   = (float*) (base + 110100480);     // [1024,256]
  float*  p0     = (float*) (base + 111149056);     // [1024,16]
  float*  r0v    = (float*) (base + 111214592);     // [1024,256]
  float*  wbv    = (float*) (base + 112263168);     // [1024,16]
  ushort* wihe_p = (ushort*)(base + 112328704);     // [832,256]
  ushort* whhe_p = (ushort*)(base + 112754688);     // [832,288]
  ushort* wihc_p = (ushort*)(base + 113233920);     // [768,256]
  ushort* whhc_p = (ushort*)(base + 113627136);     // [768,256]
  ushort* W1b    = (ushort*)(base + 114020352);     // [256,320]
  ushort* W2b    = (ushort*)(base + 114184192);     // [256,256]
  ushort* WaTb   = (ushort*)(base + 114315264);     // [256,256]
  float*  cbias  = (float*) (base + 114446336);     // [768]

  prep_all<<<4139, 256, 0, stream>>>(wih_e, whh_e, wihe_p, whhe_p,
                                     wih_c, whh_c, wihc_p, whhc_p,
                                     bih_c, bhh_c, cbias, W1, W1b, W2, W2b, Wa, WaTb);
  emb_init_r0<<<1024, 256, 0, stream>>>(lines, emb, hxs, Mbf, hbuf, p0, r0v);

  gemm_mfma<0><<<dim3(256, 13), 256, 0, stream>>>(Mbf, wihe_p, nullptr, GiAll, 256, 832);
  enc_all<<<256, 512, 0, stream>>>(GiAll, whhe_p, bih_e, bhh_e, Km, Cm, Bbf);
  accum_wb<<<1024, 256, 0, stream>>>(Bbf, Km, Kmbf, Cm, ba, wbv);
  gemm_mfma<0><<<dim3(256, 4), 256, 0, stream>>>(Kmbf, WaTb, nullptr, Ktl, 256, 256);

  build_xcat8<<<10240, 256, 0, stream>>>(cond, act, r0v, Mbf, xcat);
  gemm_mfma<1><<<dim3(1024, 4), 256, 0, stream>>>(xcat, W1b, b1, x1, 320, 256);
  gemm_mfma<1><<<dim3(1024, 4), 256, 0, stream>>>(x1, W2b, b2, x2, 256, 256);

  // cell phase: gi precompute chunks (ping-pong) + weight-stationary cell chunks
  ushort* gic[2] = {GiC0, GiC1};
  gemm_mfma<0><<<dim3(256, 12), 256, 0, stream>>>(x2 + (size_t)0*16384*256, wihc_p, cbias, gic[0], 256, 768);
  gemm_mfma<0><<<dim3(256, 12), 256, 0, stream>>>(x2 + (size_t)1*16384*256, wihc_p, cbias, gic[1], 256, 768);
  cell_chunk<<<64, 512, 0, stream>>>(gic[0], whhc_p, bhh_c, hbuf,  0, hcT, out);
  gemm_mfma<0><<<dim3(256, 12), 256, 0, stream>>>(x2 + (size_t)2*16384*256, wihc_p, cbias, gic[0], 256, 768);
  cell_chunk<<<64, 512, 0, stream>>>(gic[1], whhc_p, bhh_c, hbuf, 16, hcT, out);
  gemm_mfma<0><<<dim3(256, 12), 256, 0, stream>>>(x2 + (size_t)3*16384*256, wihc_p, cbias, gic[1], 256, 768);
  cell_chunk<<<64, 512, 0, stream>>>(gic[0], whhc_p, bhh_c, hbuf, 32, hcT, out);
  cell_chunk<<<64, 512, 0, stream>>>(gic[1], whhc_p, bhh_c, hbuf, 48, hcT, out);

  attn_v<<<1024, 256, 0, stream>>>(Ktl, hcT, wbv, Cm, p0, act, Wc, bc, out);
}